// Round 2
// baseline (166.845 us; speedup 1.0000x reference)
//
#include <hip/hip_runtime.h>
#include <math.h>

// Converse2D on gfx950 — spectral restructuring (R5):
//   out(2y+u, 2x+v) plane = ifft136( A_uv[g] * Xhat[g] ), per (n,c,u,v)
//   Xhat = rfft136x136(wrap_pad(x)); A_uv = per-channel multiplier (Hermitian).
// R5 (vs R4): inv was VALU/latency-bound (VALUBusy 45%, HBM 23%, occupancy-capped).
//   - incremental index math in all grid-stride loops (no per-iter div/mod)
//   - stage-1 twiddles read from LUT (lut[k1*n2], idx<=112) instead of serial
//     complex-multiply chains (removes ~42 VALU + dep chain per item)
//   - inv: c2r pack fused into ct68 stage-1 (paired n2 items own 8 columns)
//   - both: final store fused into stage-2 dft17 (outputs go register->global,
//     removing the LDS round-trip store loops and one barrier each)
//   - float sincosf LUT init (no f64)

#define MDIM 136
#define RSC  70             // padded LDS row stride in complex elements (69 + 1)
#define HC   69             // stored Hermitian half columns (0..68)
#define PLANE_HALF (MDIM*HC)   // 9384 complex per plane
#define NPLANES 256         // N*C
#define LDS_CPLX (MDIM*RSC + MDIM)   // z plane + cos/sin LUT (float2 each)
#define PI_D 3.14159265358979323846
#define NTH 1024

__device__ __forceinline__ int slot68(int k)  { return 17*(k & 3) + (k >> 2); }

// ---------- symmetric 17-point DFT from strided LDS, outputs via sink ----------
// X[k] = sum_n x[n] w^{kn}, w = exp(DIR*2*pi*i/17). Twiddles are compile-time
// float literals. f(k2, re, im) is called once per output k2 (k2 literal at
// each call site, so sink address math constant-folds).
template<int DIR, class F>
__device__ __forceinline__ void dft17_sink(float2* z, int base, int stride, F f)
{
    constexpr float C17[9] = {1.f, 0.93247223f, 0.73900892f, 0.44573836f,
                              0.09226836f, -0.27366299f, -0.60263464f,
                              -0.85021714f, -0.98297310f};
    constexpr float S17[9] = {0.f, 0.36124167f, 0.67369564f, 0.89516329f,
                              0.99573418f, 0.96182564f, 0.79801723f,
                              0.52643216f, 0.18374952f};
    constexpr float d = (DIR > 0) ? 1.f : -1.f;
    float xr[17], xi[17];
#pragma unroll
    for (int n = 0; n < 17; n++) {
        float2 v = z[base + n*stride];
        xr[n] = v.x; xi[n] = v.y;
    }
    float ar[8], ai[8], br[8], bi[8];
#pragma unroll
    for (int n = 1; n <= 8; n++) {
        ar[n-1] = xr[n] + xr[17-n];  ai[n-1] = xi[n] + xi[17-n];
        br[n-1] = xr[n] - xr[17-n];  bi[n-1] = xi[n] - xi[17-n];
    }
    float s0r = xr[0], s0i = xi[0];
#pragma unroll
    for (int n = 0; n < 8; n++) { s0r += ar[n]; s0i += ai[n]; }
    f(0, s0r, s0i);
#pragma unroll
    for (int k = 1; k <= 8; k++) {
        float Pr = xr[0], Pi = xi[0], Qr = 0.f, Qi = 0.f;
#pragma unroll
        for (int n = 1; n <= 8; n++) {
            int m = (k*n) % 17;                      // compile-time constant
            float cc = (m <= 8) ? C17[m] : C17[17-m];
            float ss = (m <= 8) ? S17[m] : -S17[17-m];
            Pr = fmaf(ar[n-1], cc, Pr);
            Pi = fmaf(ai[n-1], cc, Pi);
            Qr = fmaf(br[n-1], ss, Qr);
            Qi = fmaf(bi[n-1], ss, Qi);
        }
        f(k,    Pr - d*Qi, Pi + d*Qr);
        f(17-k, Pr + d*Qi, Pi - d*Qr);
    }
}

// ---------- radix-4 butterfly + LUT twiddle, write to col-slots 17*k1 + n2 ----------
template<int DIR>
__device__ __forceinline__ void radix4_tw(float2* z, const float2* lut, int base, int n2,
                                          float2 Z0, float2 Z1, float2 Z2, float2 Z3)
{
    constexpr float d = (DIR > 0) ? 1.0f : -1.0f;
    float t0r = Z0.x+Z2.x, t0i = Z0.y+Z2.y;
    float t1r = Z0.x-Z2.x, t1i = Z0.y-Z2.y;
    float t2r = Z1.x+Z3.x, t2i = Z1.y+Z3.y;
    float t3r = Z1.x-Z3.x, t3i = Z1.y-Z3.y;
    float X0r = t0r+t2r,     X0i = t0i+t2i;
    float X2r = t0r-t2r,     X2i = t0i-t2i;
    float X1r = t1r - d*t3i, X1i = t1i + d*t3r;
    float X3r = t1r + d*t3i, X3i = t1i - d*t3r;
    z[base + n2] = make_float2(X0r, X0i);
    float2 w1 = lut[2*n2], w2 = lut[4*n2], w3 = lut[6*n2];   // w68^(k1*n2), idx<=96
    z[base + 17 + n2] = make_float2(X1r*w1.x - X1i*w1.y, X1r*w1.y + X1i*w1.x);
    z[base + 34 + n2] = make_float2(X2r*w2.x - X2i*w2.y, X2r*w2.y + X2i*w2.x);
    z[base + 51 + n2] = make_float2(X3r*w3.x - X3i*w3.y, X3r*w3.y + X3i*w3.x);
}

// ---------- 136-point CT stage 1 (radix-8 + LUT twiddle) along COLUMNS ----------
template<int DIR>
__device__ void fft136_s1(float2* z, const float2* lut, int ncols, int tid)
{
    constexpr float d = (DIR > 0) ? 1.0f : -1.0f;
    constexpr float C707 = 0.70710678118654752f;
    int c = tid / 17;
    int n2 = tid - c*17;
    for (int e = tid; e < ncols*17; e += NTH) {
        float xr[8], xi[8];
#pragma unroll
        for (int n1 = 0; n1 < 8; n1++) {
            float2 v = z[(17*n1 + n2)*RSC + c];
            xr[n1] = v.x; xi[n1] = v.y;
        }
        float e0r = xr[0]+xr[4], e0i = xi[0]+xi[4];
        float e1r = xr[0]-xr[4], e1i = xi[0]-xi[4];
        float o0r = xr[2]+xr[6], o0i = xi[2]+xi[6];
        float o1r = xr[2]-xr[6], o1i = xi[2]-xi[6];
        float E0r = e0r+o0r, E0i = e0i+o0i;
        float E2r = e0r-o0r, E2i = e0i-o0i;
        float E1r = e1r - d*o1i, E1i = e1i + d*o1r;
        float E3r = e1r + d*o1i, E3i = e1i - d*o1r;
        float f0r = xr[1]+xr[5], f0i = xi[1]+xi[5];
        float f1r = xr[1]-xr[5], f1i = xi[1]-xi[5];
        float h0r = xr[3]+xr[7], h0i = xi[3]+xi[7];
        float h1r = xr[3]-xr[7], h1i = xi[3]-xi[7];
        float O0r = f0r+h0r, O0i = f0i+h0i;
        float O2r = f0r-h0r, O2i = f0i-h0i;
        float O1r = f1r - d*h1i, O1i = f1i + d*h1r;
        float O3r = f1r + d*h1i, O3i = f1i - d*h1r;
        float t1r =  C707*(O1r - d*O1i), t1i = C707*(O1i + d*O1r);
        float t2r = -d*O2i,              t2i = d*O2r;
        float t3r = -C707*(O3r + d*O3i), t3i = C707*(d*O3r - O3i);
        float Xr[8], Xi[8];
        Xr[0]=E0r+O0r; Xi[0]=E0i+O0i;  Xr[4]=E0r-O0r; Xi[4]=E0i-O0i;
        Xr[1]=E1r+t1r; Xi[1]=E1i+t1i;  Xr[5]=E1r-t1r; Xi[5]=E1i-t1i;
        Xr[2]=E2r+t2r; Xi[2]=E2i+t2i;  Xr[6]=E2r-t2r; Xi[6]=E2i-t2i;
        Xr[3]=E3r+t3r; Xi[3]=E3i+t3i;  Xr[7]=E3r-t3r; Xi[7]=E3i-t3i;
        z[n2*RSC + c] = make_float2(Xr[0], Xi[0]);
        int ti = 0;
#pragma unroll
        for (int k1 = 1; k1 < 8; k1++) {
            ti += n2;                                 // ti = k1*n2 <= 112
            float2 w = lut[ti];
            z[(17*k1 + n2)*RSC + c] = make_float2(Xr[k1]*w.x - Xi[k1]*w.y,
                                                  Xr[k1]*w.y + Xi[k1]*w.x);
        }
        c += 60; n2 += 4; if (n2 >= 17) { n2 -= 17; c++; }
    }
}

// ---------- 68-point CT stage 1 along ROWS (fwd path: natural input cols) ----------
template<int DIR>
__device__ void ct68_s1(float2* z, const float2* lut, int tid)
{
    int row = tid / 17;
    int n2  = tid - row*17;
    for (int e = tid; e < MDIM*17; e += NTH) {
        int base = row*RSC;
        float2 Z0 = z[base + n2];
        float2 Z1 = z[base + 17 + n2];
        float2 Z2 = z[base + 34 + n2];
        float2 Z3 = z[base + 51 + n2];
        radix4_tw<DIR>(z, lut, base, n2, Z0, Z1, Z2, Z3);
        row += 60; n2 += 4; if (n2 >= 17) { n2 -= 17; row++; }
    }
}

// c2r pack element: Zf[j] from a=T[j], b=T[68-j], w=lut[j] (DIR=+1 LUT).
__device__ __forceinline__ float2 c2r_pack(float2 a, float2 b, float2 w)
{
    float Sr = a.x + b.x, Si = a.y - b.y;
    float Dr = a.x - b.x, Di = a.y + b.y;
    float Or = w.x*Dr - w.y*Di, Oi = w.x*Di + w.y*Dr;
    return make_float2(Sr - Oi, Si + Or);
}

// ---------- Forward: one WG per (n,c) plane (256 WGs), r2c half-spectrum ----------
__global__ __launch_bounds__(1024, 8) void fwd_kernel(const float* __restrict__ x,
                                                      float2* __restrict__ Xhat)
{
    extern __shared__ float2 zsm[];
    float2* z   = zsm;
    float2* lut = zsm + MDIM*RSC;
    const int tid = threadIdx.x;

    if (tid < MDIM) {
        float s, c; sincosf(-2.0f*(float)PI_D*(float)tid/136.0f, &s, &c);
        lut[tid] = make_float2(c, s);
    }
    const float* xp = x + (size_t)blockIdx.x * (128*128);
    // Load packed rows: z[i][n] = xp(i, 2n) + i*xp(i, 2n+1), wrap pad by 4.
    {
        int i = tid / 68, n = tid - (tid/68)*68;
        for (int e = tid; e < MDIM*68; e += NTH) {
            int si = (i + 124) & 127;
            int j0 = (2*n + 124) & 127;              // always even, pair never wraps
            z[i*RSC + n] = *reinterpret_cast<const float2*>(xp + si*128 + j0);
            i += 15; n += 4; if (n >= 68) { n -= 68; i++; }
        }
    }
    __syncthreads();
    ct68_s1<-1>(z, lut, tid);                        // rows stage 1
    __syncthreads();
    if (tid < MDIM*4) {                              // rows stage 2: Z[k] at slot68(k)
        int row = tid >> 2, k1 = tid & 3;
        int base = row*RSC + 17*k1;
        dft17_sink<-1>(z, base, 1, [&](int k2, float re, float im) {
            z[base + k2] = make_float2(re, im);
        });
    }
    __syncthreads();
    // r2c unpack: X[k] = E + w136^k * O ; item k handles (k, 68-k), in-place at slots.
    {
        int row = tid / 35, k = tid - (tid/35)*35;
        for (int e = tid; e < MDIM*35; e += NTH) {
            int base = row*RSC;
            int sa = slot68(k);
            float2 Za = z[base+sa];
            float Zar = Za.x, Zai = Za.y;
            float Zbr, Zbi; int sb;
            if (k == 0) { Zbr = Zar; Zbi = Zai; sb = 68; }  // Z[68]==Z[0]; X[68]->col 68
            else {
                int kk = 68-k; sb = slot68(kk);
                float2 Zb = z[base+sb]; Zbr = Zb.x; Zbi = Zb.y;
            }
            float2 w = lut[k];                              // w136^k (DIR=-1 LUT)
            float wc = w.x, ws = w.y;
            float Er = 0.5f*(Zar + Zbr), Ei = 0.5f*(Zai - Zbi);
            float Dr = 0.5f*(Zar - Zbr), Di = 0.5f*(Zai + Zbi);
            float Tr = wc*Dr - ws*Di, Ti = wc*Di + ws*Dr;   // w^k * D
            z[base+sa] = make_float2(Er + Ti, Ei - Tr);     // X[k] = E - i*(w^k D)
            float E2r = Er,  E2i = -Ei;
            float D2r = -Dr, D2i = Di;
            float w2c = -wc, w2s = ws;                      // w136^(68-k) = -conj(w^k)
            float T2r = w2c*D2r - w2s*D2i, T2i = w2c*D2i + w2s*D2r;
            z[base+sb] = make_float2(E2r + T2i, E2i - T2r); // X[68-k]
            row += 29; k += 9; if (k >= 35) { k -= 35; row++; }
        }
    }
    __syncthreads();
    fft136_s1<-1>(z, lut, HC, tid);                  // columns stage 1 (69 cols)
    __syncthreads();
    // Columns stage 2 fused with Xhat store: X[k2] -> g1 = k1 + 8*k2, natural g2.
    float2* outp = Xhat + (size_t)blockIdx.x * PLANE_HALF;
    if (tid < HC*8) {
        int c = tid >> 3, k1 = tid & 7;
        int cd = (c*241) >> 12;                      // c/17 for c<=68
        int cm = c - 17*cd;
        int g2 = (c == 68) ? 68 : (4*cm + cd);       // inverse slot68
        float2* op2 = outp + g2;
        dft17_sink<-1>(z, 17*k1*RSC + c, RSC, [&](int k2, float re, float im) {
            op2[(size_t)(k1 + 8*k2)*HC] = make_float2(re, im);
        });
    }
}

// ---------- Per-channel multiplier precompute (double, table-driven trig) ----------
__global__ void prep_kernel(const float* __restrict__ weight,
                            const float* __restrict__ bias,
                            float2* __restrict__ Abuf)
{
    __shared__ double tabc[272], tabs[272];   // exp(-2*pi*i*t/272)
    for (int t = threadIdx.x; t < 272; t += blockDim.x) {
        double s, c; sincos(-2.0*PI_D*(double)t/272.0, &s, &c);
        tabc[t] = c; tabs[t] = s;
    }
    __syncthreads();

    const int c     = blockIdx.x >> 3;
    const int chunk = blockIdx.x & 7;
    const float* wp = weight + c*25;
    double w[25];
#pragma unroll
    for (int i = 0; i < 25; i++) w[i] = (double)wp[i];
    const double r = 1.0/(1.0 + exp(9.0 - (double)bias[c])) + 1e-5;

    const int e_lo = chunk * 1173;           // 8*1173 == PLANE_HALF
    const int e_hi = e_lo + 1173;
    for (int e = e_lo + (int)threadIdx.x; e < e_hi; e += blockDim.x) {
        int g1 = e / HC, g2 = e - g1*HC;
        double c1 = tabc[g1], s1 = tabs[g1];
        double c2 = tabc[g2], s2 = tabs[g2];
        double e1r[5], e1i[5], e2r[5], e2i[5];
        e1r[2]=1.0; e1i[2]=0.0; e1r[3]=c1; e1i[3]=s1;
        e1r[4]=c1*c1-s1*s1; e1i[4]=2.0*c1*s1;
        e1r[1]=c1; e1i[1]=-s1; e1r[0]=e1r[4]; e1i[0]=-e1i[4];
        e2r[2]=1.0; e2i[2]=0.0; e2r[3]=c2; e2i[3]=s2;
        e2r[4]=c2*c2-s2*s2; e2i[4]=2.0*c2*s2;
        e2r[1]=c2; e2i[1]=-s2; e2r[0]=e2r[4]; e2i[0]=-e2i[4];

        double R0r[5],R0i[5],R1r[5],R1i[5];
#pragma unroll
        for (int a = 0; a < 5; a++) {
            double r0r=0,r0i=0,r1r=0,r1i=0;
#pragma unroll
            for (int b = 0; b < 5; b++) {
                double wv = w[a*5+b];
                double pr = wv*e2r[b], pi = wv*e2i[b];
                r0r += pr; r0i += pi;
                if (b & 1) { r1r -= pr; r1i -= pi; } else { r1r += pr; r1i += pi; }
            }
            R0r[a]=r0r; R0i[a]=r0i; R1r[a]=r1r; R1i[a]=r1i;
        }
        double FBr[2][2], FBi[2][2];
#pragma unroll
        for (int a1 = 0; a1 < 2; a1++)
#pragma unroll
            for (int b1 = 0; b1 < 2; b1++) {
                double fr=0, fi=0;
#pragma unroll
                for (int a = 0; a < 5; a++) {
                    double er = e1r[a], ei = e1i[a];
                    if (a1 && (a & 1)) { er = -er; ei = -ei; }
                    double Rr = b1 ? R1r[a] : R0r[a];
                    double Ri = b1 ? R1i[a] : R0i[a];
                    fr += er*Rr - ei*Ri;
                    fi += er*Ri + ei*Rr;
                }
                FBr[a1][b1]=fr; FBi[a1][b1]=fi;
            }
        double ur[2]={1.0+c1, 1.0-c1}, ui[2]={s1, -s1};
        double vr[2]={1.0+c2, 1.0-c2}, vi[2]={s2, -s2};
        double Br_[2][2], Bi_[2][2];
#pragma unroll
        for (int a1 = 0; a1 < 2; a1++)
#pragma unroll
            for (int b1 = 0; b1 < 2; b1++) {
                Br_[a1][b1] = ur[a1]*vr[b1] - ui[a1]*vi[b1];
                Bi_[a1][b1] = ur[a1]*vi[b1] + ui[a1]*vr[b1];
            }
        double invW=0, Qr=0, Qi=0;
#pragma unroll
        for (int a1 = 0; a1 < 2; a1++)
#pragma unroll
            for (int b1 = 0; b1 < 2; b1++) {
                invW += FBr[a1][b1]*FBr[a1][b1] + FBi[a1][b1]*FBi[a1][b1];
                Qr += FBr[a1][b1]*Br_[a1][b1] - FBi[a1][b1]*Bi_[a1][b1];
                Qi += FBr[a1][b1]*Bi_[a1][b1] + FBi[a1][b1]*Br_[a1][b1];
            }
        invW *= 0.25; Qr *= 0.25; Qi *= 0.25;
        double den = 1.0/(invW + r);
        double Sr = (1.0 - Qr)*den, Si = -Qi*den;
        double Mr[2][2], Mi[2][2];
#pragma unroll
        for (int a1 = 0; a1 < 2; a1++)
#pragma unroll
            for (int b1 = 0; b1 < 2; b1++) {
                Mr[a1][b1] = Br_[a1][b1] + FBr[a1][b1]*Sr + FBi[a1][b1]*Si;
                Mi[a1][b1] = Bi_[a1][b1] + FBr[a1][b1]*Si - FBi[a1][b1]*Sr;
            }
        const double scale = 1.0/73984.0;   // 1/272^2 ifft normalization
#pragma unroll
        for (int uu = 0; uu < 2; uu++)
#pragma unroll
            for (int vv = 0; vv < 2; vv++) {
                double sr=0, si=0;
#pragma unroll
                for (int a1 = 0; a1 < 2; a1++)
#pragma unroll
                    for (int b1 = 0; b1 < 2; b1++) {
                        if ((a1*uu + b1*vv) & 1) { sr -= Mr[a1][b1]; si -= Mi[a1][b1]; }
                        else                     { sr += Mr[a1][b1]; si += Mi[a1][b1]; }
                    }
                int t = g1*uu + g2*vv;                 // <= 203 < 272
                double pc = tabc[t], ps = -tabs[t];    // exp(+i*pi*t/136)
                float2 outv;
                outv.x = (float)((pc*sr - ps*si)*scale);
                outv.y = (float)((pc*si + ps*sr)*scale);
                Abuf[((size_t)(c*4 + uu*2 + vv))*PLANE_HALF + e] = outv;
            }
    }
}

// ---------- Inverse: one WG per (n,c,u,v) (1024 WGs), Hermitian half-spectrum ----------
// blockIdx swizzle: v = bit 3 so the v-pair (same nc,u) is 8 apart -> same XCD
// (blockIdx%8 round-robin) -> their interleaved partial-line writes merge in L2.
__global__ __launch_bounds__(1024, 8) void inv_kernel(const float2* __restrict__ Xhat,
                                                      const float2* __restrict__ Abuf,
                                                      float* __restrict__ out)
{
    extern __shared__ float2 zsm[];
    float2* z   = zsm;
    float2* lut = zsm + MDIM*RSC;
    const int tid = threadIdx.x;

    if (tid < MDIM) {
        float s, c; sincosf(2.0f*(float)PI_D*(float)tid/136.0f, &s, &c);  // inverse dir
        lut[tid] = make_float2(c, s);
    }
    const int p  = blockIdx.x;        // 0..1023
    const int u  = p & 1;
    const int v  = (p >> 3) & 1;
    const int nc = ((p >> 4) << 2) | ((p >> 1) & 3);   // n*64 + c
    const int c  = nc & 63;
    const float2* Xp = Xhat + (size_t)nc * PLANE_HALF;
    const float2* Ap = Abuf + (size_t)(c*4 + u*2 + v) * PLANE_HALF;

    // Load S = A_uv * Xhat, natural [g1][g2], g2 = 0..68. (S is Hermitian.)
    {
        int g1 = tid / HC, g2 = tid - (tid/HC)*HC;
        for (int e = tid; e < PLANE_HALF; e += NTH) {
            float2 xv = Xp[e], av = Ap[e];
            z[g1*RSC + g2] = make_float2(av.x*xv.x - av.y*xv.y,
                                         av.x*xv.y + av.y*xv.x);
            g1 += 14; g2 += 58; if (g2 >= HC) { g2 -= HC; g1++; }
        }
    }
    __syncthreads();
    fft136_s1<1>(z, lut, HC, tid);                   // columns stage 1
    __syncthreads();
    if (tid < HC*8) {                                // columns stage 2 (rows->slot136)
        int cc = tid >> 3, k1 = tid & 7;
        int base = 17*k1*RSC + cc;
        dft17_sink<1>(z, base, RSC, [&](int k2, float re, float im) {
            z[base + k2*RSC] = make_float2(re, im);
        });
    }
    __syncthreads();
    // Fused c2r pack + ct68 stage 1 (rows): item (row, g) owns column residues
    // {g, 17-g} mod 17; computes Zf[j] = c2r(T[j], T[68-j], lut[j]) inline for its
    // 8 (or 4) columns, then both radix-4 butterflies. Col 68 is read-only.
    {
        int row = tid / 9, g = tid - (tid/9)*9;
        for (int e = tid; e < MDIM*9; e += NTH) {
            int base = row*RSC;
            if (g == 0) {
                float2 T0  = z[base],    T17 = z[base+17], T34 = z[base+34],
                       T51 = z[base+51], T68 = z[base+68];
                float2 Z0 = c2r_pack(T0,  T68, lut[0]);
                float2 Z1 = c2r_pack(T17, T51, lut[17]);
                float2 Z2 = c2r_pack(T34, T34, lut[34]);
                float2 Z3 = c2r_pack(T51, T17, lut[51]);
                radix4_tw<1>(z, lut, base, 0, Z0, Z1, Z2, Z3);
            } else {
                int gb = 17 - g;
                float2 Ta0 = z[base+g],    Ta1 = z[base+g+17],
                       Ta2 = z[base+g+34], Ta3 = z[base+g+51];
                float2 Tb0 = z[base+gb],    Tb1 = z[base+gb+17],
                       Tb2 = z[base+gb+34], Tb3 = z[base+gb+51];
                // partner of (g+17*n1) is (gb+17*(3-n1)), and vice versa
                float2 Za0 = c2r_pack(Ta0, Tb3, lut[g]);
                float2 Za1 = c2r_pack(Ta1, Tb2, lut[g+17]);
                float2 Za2 = c2r_pack(Ta2, Tb1, lut[g+34]);
                float2 Za3 = c2r_pack(Ta3, Tb0, lut[g+51]);
                float2 Zb0 = c2r_pack(Tb0, Ta3, lut[gb]);
                float2 Zb1 = c2r_pack(Tb1, Ta2, lut[gb+17]);
                float2 Zb2 = c2r_pack(Tb2, Ta1, lut[gb+34]);
                float2 Zb3 = c2r_pack(Tb3, Ta0, lut[gb+51]);
                radix4_tw<1>(z, lut, base, g,  Za0, Za1, Za2, Za3);
                radix4_tw<1>(z, lut, base, gb, Zb0, Zb1, Zb2, Zb3);
            }
            row += 113; g += 7; if (g >= 9) { g -= 9; row++; }
        }
    }
    __syncthreads();
    // ct68 stage 2 fused with cropped store: X[k2] -> m = k1 + 4*k2;
    // physical row r -> y1 = 8*(r%17) + r/17; keep y1 in [4,132), m in [2,66).
    float* op = out + (size_t)nc * (256*256);
    if (tid < MDIM*4) {
        int row = tid >> 2, k1 = tid & 3;
        int rq = (row*241) >> 12;                    // row/17
        int rm = row - 17*rq;
        int y1 = 8*rm + rq;
        if (y1 >= 4 && y1 < 132) {
            float* rowp = op + (size_t)(2*y1 + u - 8)*256 + v - 8;
            dft17_sink<1>(z, row*RSC + 17*k1, 1, [&](int k2, float re, float im) {
                int m = k1 + 4*k2;
                if (m >= 2 && m < 66) {
                    rowp[4*m]     = re;              // y2' = 2m
                    rowp[4*m + 2] = im;              // y2' = 2m+1
                }
            });
        }
    }
}

extern "C" void kernel_launch(void* const* d_in, const int* in_sizes, int n_in,
                              void* d_out, int out_size, void* d_ws, size_t ws_size,
                              hipStream_t stream)
{
    const float* x      = (const float*)d_in[0];
    const float* weight = (const float*)d_in[1];
    const float* bias   = (const float*)d_in[2];
    float* out = (float*)d_out;

    float2* Xhat = (float2*)d_ws;                       // 256 * 9384 * 8B = 19.2 MB
    float2* Abuf = Xhat + (size_t)NPLANES * PLANE_HALF; // 256 * 9384 * 8B = 19.2 MB

    const size_t lds_bytes = (size_t)LDS_CPLX * sizeof(float2);  // 77,248 B
    (void)hipFuncSetAttribute((const void*)fwd_kernel,
                              hipFuncAttributeMaxDynamicSharedMemorySize, (int)lds_bytes);
    (void)hipFuncSetAttribute((const void*)inv_kernel,
                              hipFuncAttributeMaxDynamicSharedMemorySize, (int)lds_bytes);

    prep_kernel<<<512, 256, 0, stream>>>(weight, bias, Abuf);
    fwd_kernel<<<NPLANES, 1024, lds_bytes, stream>>>(x, Xhat);
    inv_kernel<<<NPLANES*4, 1024, lds_bytes, stream>>>(Xhat, Abuf, out);
}

// Round 3
// 150.261 us; speedup vs baseline: 1.1104x; 1.1104x over previous
//
#include <hip/hip_runtime.h>
#include <math.h>

// Converse2D on gfx950 — spectral restructuring (R6):
//   out(2y+u, 2x+v) plane = ifft136( A_uv[g] * Xhat[g] ), per (n,c,u,v)
//   Xhat = rfft136x136(wrap_pad(x)); A_uv = per-channel multiplier (Hermitian).
// R6 = R5 minus the store-fusion regression:
//   KEPT: incremental index math, LUT stage-1 twiddles, c2r pack fused into
//         ct68 stage-1 (inv), sincosf LUT init.
//   REVERTED: stage-2 dft17 is in-place LDS again; global stores are separate
//         all-1024-thread coalesced loops (R5's 544-thread scalar-scatter fused
//         stores dropped VALUBusy 45->33% and cost +11us on inv).
//   NEW: inv final-store loop strength-reduced (m fixed per thread, y1 += 16
//        per iter -> LDS addr += 2*RSC, global ptr += 32*256).

#define MDIM 136
#define RSC  70             // padded LDS row stride in complex elements (69 + 1)
#define HC   69             // stored Hermitian half columns (0..68)
#define PLANE_HALF (MDIM*HC)   // 9384 complex per plane
#define NPLANES 256         // N*C
#define LDS_CPLX (MDIM*RSC + MDIM)   // z plane + cos/sin LUT (float2 each)
#define PI_D 3.14159265358979323846
#define NTH 1024

__device__ __forceinline__ int slot136(int k) { return 17*(k & 7) + (k >> 3); }
__device__ __forceinline__ int slot68(int k)  { return 17*(k & 3) + (k >> 2); }

// ---------- symmetric 17-point DFT from strided LDS, outputs via sink ----------
// X[k] = sum_n x[n] w^{kn}, w = exp(DIR*2*pi*i/17). Twiddles are compile-time
// float literals. f(k2, re, im) is called once per output k2 (k2 literal at
// each call site, so sink address math constant-folds).
template<int DIR, class F>
__device__ __forceinline__ void dft17_sink(float2* z, int base, int stride, F f)
{
    constexpr float C17[9] = {1.f, 0.93247223f, 0.73900892f, 0.44573836f,
                              0.09226836f, -0.27366299f, -0.60263464f,
                              -0.85021714f, -0.98297310f};
    constexpr float S17[9] = {0.f, 0.36124167f, 0.67369564f, 0.89516329f,
                              0.99573418f, 0.96182564f, 0.79801723f,
                              0.52643216f, 0.18374952f};
    constexpr float d = (DIR > 0) ? 1.f : -1.f;
    float xr[17], xi[17];
#pragma unroll
    for (int n = 0; n < 17; n++) {
        float2 v = z[base + n*stride];
        xr[n] = v.x; xi[n] = v.y;
    }
    float ar[8], ai[8], br[8], bi[8];
#pragma unroll
    for (int n = 1; n <= 8; n++) {
        ar[n-1] = xr[n] + xr[17-n];  ai[n-1] = xi[n] + xi[17-n];
        br[n-1] = xr[n] - xr[17-n];  bi[n-1] = xi[n] - xi[17-n];
    }
    float s0r = xr[0], s0i = xi[0];
#pragma unroll
    for (int n = 0; n < 8; n++) { s0r += ar[n]; s0i += ai[n]; }
    f(0, s0r, s0i);
#pragma unroll
    for (int k = 1; k <= 8; k++) {
        float Pr = xr[0], Pi = xi[0], Qr = 0.f, Qi = 0.f;
#pragma unroll
        for (int n = 1; n <= 8; n++) {
            int m = (k*n) % 17;                      // compile-time constant
            float cc = (m <= 8) ? C17[m] : C17[17-m];
            float ss = (m <= 8) ? S17[m] : -S17[17-m];
            Pr = fmaf(ar[n-1], cc, Pr);
            Pi = fmaf(ai[n-1], cc, Pi);
            Qr = fmaf(br[n-1], ss, Qr);
            Qi = fmaf(bi[n-1], ss, Qi);
        }
        f(k,    Pr - d*Qi, Pi + d*Qr);
        f(17-k, Pr + d*Qi, Pi - d*Qr);
    }
}

// ---------- radix-4 butterfly + LUT twiddle, write to col-slots 17*k1 + n2 ----------
template<int DIR>
__device__ __forceinline__ void radix4_tw(float2* z, const float2* lut, int base, int n2,
                                          float2 Z0, float2 Z1, float2 Z2, float2 Z3)
{
    constexpr float d = (DIR > 0) ? 1.0f : -1.0f;
    float t0r = Z0.x+Z2.x, t0i = Z0.y+Z2.y;
    float t1r = Z0.x-Z2.x, t1i = Z0.y-Z2.y;
    float t2r = Z1.x+Z3.x, t2i = Z1.y+Z3.y;
    float t3r = Z1.x-Z3.x, t3i = Z1.y-Z3.y;
    float X0r = t0r+t2r,     X0i = t0i+t2i;
    float X2r = t0r-t2r,     X2i = t0i-t2i;
    float X1r = t1r - d*t3i, X1i = t1i + d*t3r;
    float X3r = t1r + d*t3i, X3i = t1i - d*t3r;
    z[base + n2] = make_float2(X0r, X0i);
    float2 w1 = lut[2*n2], w2 = lut[4*n2], w3 = lut[6*n2];   // w68^(k1*n2), idx<=96
    z[base + 17 + n2] = make_float2(X1r*w1.x - X1i*w1.y, X1r*w1.y + X1i*w1.x);
    z[base + 34 + n2] = make_float2(X2r*w2.x - X2i*w2.y, X2r*w2.y + X2i*w2.x);
    z[base + 51 + n2] = make_float2(X3r*w3.x - X3i*w3.y, X3r*w3.y + X3i*w3.x);
}

// ---------- 136-point CT stage 1 (radix-8 + LUT twiddle) along COLUMNS ----------
template<int DIR>
__device__ void fft136_s1(float2* z, const float2* lut, int ncols, int tid)
{
    constexpr float d = (DIR > 0) ? 1.0f : -1.0f;
    constexpr float C707 = 0.70710678118654752f;
    int c = tid / 17;
    int n2 = tid - c*17;
    for (int e = tid; e < ncols*17; e += NTH) {
        float xr[8], xi[8];
#pragma unroll
        for (int n1 = 0; n1 < 8; n1++) {
            float2 v = z[(17*n1 + n2)*RSC + c];
            xr[n1] = v.x; xi[n1] = v.y;
        }
        float e0r = xr[0]+xr[4], e0i = xi[0]+xi[4];
        float e1r = xr[0]-xr[4], e1i = xi[0]-xi[4];
        float o0r = xr[2]+xr[6], o0i = xi[2]+xi[6];
        float o1r = xr[2]-xr[6], o1i = xi[2]-xi[6];
        float E0r = e0r+o0r, E0i = e0i+o0i;
        float E2r = e0r-o0r, E2i = e0i-o0i;
        float E1r = e1r - d*o1i, E1i = e1i + d*o1r;
        float E3r = e1r + d*o1i, E3i = e1i - d*o1r;
        float f0r = xr[1]+xr[5], f0i = xi[1]+xi[5];
        float f1r = xr[1]-xr[5], f1i = xi[1]-xi[5];
        float h0r = xr[3]+xr[7], h0i = xi[3]+xi[7];
        float h1r = xr[3]-xr[7], h1i = xi[3]-xi[7];
        float O0r = f0r+h0r, O0i = f0i+h0i;
        float O2r = f0r-h0r, O2i = f0i-h0i;
        float O1r = f1r - d*h1i, O1i = f1i + d*h1r;
        float O3r = f1r + d*h1i, O3i = f1i - d*h1r;
        float t1r =  C707*(O1r - d*O1i), t1i = C707*(O1i + d*O1r);
        float t2r = -d*O2i,              t2i = d*O2r;
        float t3r = -C707*(O3r + d*O3i), t3i = C707*(d*O3r - O3i);
        float Xr[8], Xi[8];
        Xr[0]=E0r+O0r; Xi[0]=E0i+O0i;  Xr[4]=E0r-O0r; Xi[4]=E0i-O0i;
        Xr[1]=E1r+t1r; Xi[1]=E1i+t1i;  Xr[5]=E1r-t1r; Xi[5]=E1i-t1i;
        Xr[2]=E2r+t2r; Xi[2]=E2i+t2i;  Xr[6]=E2r-t2r; Xi[6]=E2i-t2i;
        Xr[3]=E3r+t3r; Xi[3]=E3i+t3i;  Xr[7]=E3r-t3r; Xi[7]=E3i-t3i;
        z[n2*RSC + c] = make_float2(Xr[0], Xi[0]);
        int ti = 0;
#pragma unroll
        for (int k1 = 1; k1 < 8; k1++) {
            ti += n2;                                 // ti = k1*n2 <= 112
            float2 w = lut[ti];
            z[(17*k1 + n2)*RSC + c] = make_float2(Xr[k1]*w.x - Xi[k1]*w.y,
                                                  Xr[k1]*w.y + Xi[k1]*w.x);
        }
        c += 60; n2 += 4; if (n2 >= 17) { n2 -= 17; c++; }
    }
}

// ---------- 68-point CT stage 1 along ROWS (fwd path: natural input cols) ----------
template<int DIR>
__device__ void ct68_s1(float2* z, const float2* lut, int tid)
{
    int row = tid / 17;
    int n2  = tid - row*17;
    for (int e = tid; e < MDIM*17; e += NTH) {
        int base = row*RSC;
        float2 Z0 = z[base + n2];
        float2 Z1 = z[base + 17 + n2];
        float2 Z2 = z[base + 34 + n2];
        float2 Z3 = z[base + 51 + n2];
        radix4_tw<DIR>(z, lut, base, n2, Z0, Z1, Z2, Z3);
        row += 60; n2 += 4; if (n2 >= 17) { n2 -= 17; row++; }
    }
}

// c2r pack element: Zf[j] from a=T[j], b=T[68-j], w=lut[j] (DIR=+1 LUT).
__device__ __forceinline__ float2 c2r_pack(float2 a, float2 b, float2 w)
{
    float Sr = a.x + b.x, Si = a.y - b.y;
    float Dr = a.x - b.x, Di = a.y + b.y;
    float Or = w.x*Dr - w.y*Di, Oi = w.x*Di + w.y*Dr;
    return make_float2(Sr - Oi, Si + Or);
}

// ---------- Forward: one WG per (n,c) plane (256 WGs), r2c half-spectrum ----------
__global__ __launch_bounds__(1024, 8) void fwd_kernel(const float* __restrict__ x,
                                                      float2* __restrict__ Xhat)
{
    extern __shared__ float2 zsm[];
    float2* z   = zsm;
    float2* lut = zsm + MDIM*RSC;
    const int tid = threadIdx.x;

    if (tid < MDIM) {
        float s, c; sincosf(-2.0f*(float)PI_D*(float)tid/136.0f, &s, &c);
        lut[tid] = make_float2(c, s);
    }
    const float* xp = x + (size_t)blockIdx.x * (128*128);
    // Load packed rows: z[i][n] = xp(i, 2n) + i*xp(i, 2n+1), wrap pad by 4.
    {
        int i = tid / 68, n = tid - (tid/68)*68;
        for (int e = tid; e < MDIM*68; e += NTH) {
            int si = (i + 124) & 127;
            int j0 = (2*n + 124) & 127;              // always even, pair never wraps
            z[i*RSC + n] = *reinterpret_cast<const float2*>(xp + si*128 + j0);
            i += 15; n += 4; if (n >= 68) { n -= 68; i++; }
        }
    }
    __syncthreads();
    ct68_s1<-1>(z, lut, tid);                        // rows stage 1
    __syncthreads();
    if (tid < MDIM*4) {                              // rows stage 2: Z[k] at slot68(k)
        int row = tid >> 2, k1 = tid & 3;
        int base = row*RSC + 17*k1;
        dft17_sink<-1>(z, base, 1, [&](int k2, float re, float im) {
            z[base + k2] = make_float2(re, im);
        });
    }
    __syncthreads();
    // r2c unpack: X[k] = E + w136^k * O ; item k handles (k, 68-k), in-place at slots.
    {
        int row = tid / 35, k = tid - (tid/35)*35;
        for (int e = tid; e < MDIM*35; e += NTH) {
            int base = row*RSC;
            int sa = slot68(k);
            float2 Za = z[base+sa];
            float Zar = Za.x, Zai = Za.y;
            float Zbr, Zbi; int sb;
            if (k == 0) { Zbr = Zar; Zbi = Zai; sb = 68; }  // Z[68]==Z[0]; X[68]->col 68
            else {
                int kk = 68-k; sb = slot68(kk);
                float2 Zb = z[base+sb]; Zbr = Zb.x; Zbi = Zb.y;
            }
            float2 w = lut[k];                              // w136^k (DIR=-1 LUT)
            float wc = w.x, ws = w.y;
            float Er = 0.5f*(Zar + Zbr), Ei = 0.5f*(Zai - Zbi);
            float Dr = 0.5f*(Zar - Zbr), Di = 0.5f*(Zai + Zbi);
            float Tr = wc*Dr - ws*Di, Ti = wc*Di + ws*Dr;   // w^k * D
            z[base+sa] = make_float2(Er + Ti, Ei - Tr);     // X[k] = E - i*(w^k D)
            float E2r = Er,  E2i = -Ei;
            float D2r = -Dr, D2i = Di;
            float w2c = -wc, w2s = ws;                      // w136^(68-k) = -conj(w^k)
            float T2r = w2c*D2r - w2s*D2i, T2i = w2c*D2i + w2s*D2r;
            z[base+sb] = make_float2(E2r + T2i, E2i - T2r); // X[68-k]
            row += 29; k += 9; if (k >= 35) { k -= 35; row++; }
        }
    }
    __syncthreads();
    fft136_s1<-1>(z, lut, HC, tid);                  // columns stage 1 (69 cols)
    __syncthreads();
    if (tid < HC*8) {                                // columns stage 2, in place:
        int c = tid >> 3, k1 = tid & 7;              // freq k1+8k2 at row-slot 17k1+k2
        int base = 17*k1*RSC + c;
        dft17_sink<-1>(z, base, RSC, [&](int k2, float re, float im) {
            z[base + k2*RSC] = make_float2(re, im);
        });
    }
    __syncthreads();
    // Coalesced Xhat store: outp[g1*HC+g2] = z[slot136(g1)*RSC + colslot(g2)].
    float2* outp = Xhat + (size_t)blockIdx.x * PLANE_HALF;
    {
        int g1 = tid / HC, g2 = tid - (tid/HC)*HC;
        for (int e = tid; e < PLANE_HALF; e += NTH) {
            int cq = (g2 == 68) ? 68 : slot68(g2);
            outp[e] = z[slot136(g1)*RSC + cq];
            g1 += 14; g2 += 58; if (g2 >= HC) { g2 -= HC; g1++; }
        }
    }
}

// ---------- Per-channel multiplier precompute (double, table-driven trig) ----------
__global__ void prep_kernel(const float* __restrict__ weight,
                            const float* __restrict__ bias,
                            float2* __restrict__ Abuf)
{
    __shared__ double tabc[272], tabs[272];   // exp(-2*pi*i*t/272)
    for (int t = threadIdx.x; t < 272; t += blockDim.x) {
        double s, c; sincos(-2.0*PI_D*(double)t/272.0, &s, &c);
        tabc[t] = c; tabs[t] = s;
    }
    __syncthreads();

    const int c     = blockIdx.x >> 3;
    const int chunk = blockIdx.x & 7;
    const float* wp = weight + c*25;
    double w[25];
#pragma unroll
    for (int i = 0; i < 25; i++) w[i] = (double)wp[i];
    const double r = 1.0/(1.0 + exp(9.0 - (double)bias[c])) + 1e-5;

    const int e_lo = chunk * 1173;           // 8*1173 == PLANE_HALF
    const int e_hi = e_lo + 1173;
    for (int e = e_lo + (int)threadIdx.x; e < e_hi; e += blockDim.x) {
        int g1 = e / HC, g2 = e - g1*HC;
        double c1 = tabc[g1], s1 = tabs[g1];
        double c2 = tabc[g2], s2 = tabs[g2];
        double e1r[5], e1i[5], e2r[5], e2i[5];
        e1r[2]=1.0; e1i[2]=0.0; e1r[3]=c1; e1i[3]=s1;
        e1r[4]=c1*c1-s1*s1; e1i[4]=2.0*c1*s1;
        e1r[1]=c1; e1i[1]=-s1; e1r[0]=e1r[4]; e1i[0]=-e1i[4];
        e2r[2]=1.0; e2i[2]=0.0; e2r[3]=c2; e2i[3]=s2;
        e2r[4]=c2*c2-s2*s2; e2i[4]=2.0*c2*s2;
        e2r[1]=c2; e2i[1]=-s2; e2r[0]=e2r[4]; e2i[0]=-e2i[4];

        double R0r[5],R0i[5],R1r[5],R1i[5];
#pragma unroll
        for (int a = 0; a < 5; a++) {
            double r0r=0,r0i=0,r1r=0,r1i=0;
#pragma unroll
            for (int b = 0; b < 5; b++) {
                double wv = w[a*5+b];
                double pr = wv*e2r[b], pi = wv*e2i[b];
                r0r += pr; r0i += pi;
                if (b & 1) { r1r -= pr; r1i -= pi; } else { r1r += pr; r1i += pi; }
            }
            R0r[a]=r0r; R0i[a]=r0i; R1r[a]=r1r; R1i[a]=r1i;
        }
        double FBr[2][2], FBi[2][2];
#pragma unroll
        for (int a1 = 0; a1 < 2; a1++)
#pragma unroll
            for (int b1 = 0; b1 < 2; b1++) {
                double fr=0, fi=0;
#pragma unroll
                for (int a = 0; a < 5; a++) {
                    double er = e1r[a], ei = e1i[a];
                    if (a1 && (a & 1)) { er = -er; ei = -ei; }
                    double Rr = b1 ? R1r[a] : R0r[a];
                    double Ri = b1 ? R1i[a] : R0i[a];
                    fr += er*Rr - ei*Ri;
                    fi += er*Ri + ei*Rr;
                }
                FBr[a1][b1]=fr; FBi[a1][b1]=fi;
            }
        double ur[2]={1.0+c1, 1.0-c1}, ui[2]={s1, -s1};
        double vr[2]={1.0+c2, 1.0-c2}, vi[2]={s2, -s2};
        double Br_[2][2], Bi_[2][2];
#pragma unroll
        for (int a1 = 0; a1 < 2; a1++)
#pragma unroll
            for (int b1 = 0; b1 < 2; b1++) {
                Br_[a1][b1] = ur[a1]*vr[b1] - ui[a1]*vi[b1];
                Bi_[a1][b1] = ur[a1]*vi[b1] + ui[a1]*vr[b1];
            }
        double invW=0, Qr=0, Qi=0;
#pragma unroll
        for (int a1 = 0; a1 < 2; a1++)
#pragma unroll
            for (int b1 = 0; b1 < 2; b1++) {
                invW += FBr[a1][b1]*FBr[a1][b1] + FBi[a1][b1]*FBi[a1][b1];
                Qr += FBr[a1][b1]*Br_[a1][b1] - FBi[a1][b1]*Bi_[a1][b1];
                Qi += FBr[a1][b1]*Bi_[a1][b1] + FBi[a1][b1]*Br_[a1][b1];
            }
        invW *= 0.25; Qr *= 0.25; Qi *= 0.25;
        double den = 1.0/(invW + r);
        double Sr = (1.0 - Qr)*den, Si = -Qi*den;
        double Mr[2][2], Mi[2][2];
#pragma unroll
        for (int a1 = 0; a1 < 2; a1++)
#pragma unroll
            for (int b1 = 0; b1 < 2; b1++) {
                Mr[a1][b1] = Br_[a1][b1] + FBr[a1][b1]*Sr + FBi[a1][b1]*Si;
                Mi[a1][b1] = Bi_[a1][b1] + FBr[a1][b1]*Si - FBi[a1][b1]*Sr;
            }
        const double scale = 1.0/73984.0;   // 1/272^2 ifft normalization
#pragma unroll
        for (int uu = 0; uu < 2; uu++)
#pragma unroll
            for (int vv = 0; vv < 2; vv++) {
                double sr=0, si=0;
#pragma unroll
                for (int a1 = 0; a1 < 2; a1++)
#pragma unroll
                    for (int b1 = 0; b1 < 2; b1++) {
                        if ((a1*uu + b1*vv) & 1) { sr -= Mr[a1][b1]; si -= Mi[a1][b1]; }
                        else                     { sr += Mr[a1][b1]; si += Mi[a1][b1]; }
                    }
                int t = g1*uu + g2*vv;                 // <= 203 < 272
                double pc = tabc[t], ps = -tabs[t];    // exp(+i*pi*t/136)
                float2 outv;
                outv.x = (float)((pc*sr - ps*si)*scale);
                outv.y = (float)((pc*si + ps*sr)*scale);
                Abuf[((size_t)(c*4 + uu*2 + vv))*PLANE_HALF + e] = outv;
            }
    }
}

// ---------- Inverse: one WG per (n,c,u,v) (1024 WGs), Hermitian half-spectrum ----------
// blockIdx swizzle: v = bit 3 so the v-pair (same nc,u) is 8 apart -> same XCD
// (blockIdx%8 round-robin) -> their interleaved partial-line writes merge in L2.
__global__ __launch_bounds__(1024, 8) void inv_kernel(const float2* __restrict__ Xhat,
                                                      const float2* __restrict__ Abuf,
                                                      float* __restrict__ out)
{
    extern __shared__ float2 zsm[];
    float2* z   = zsm;
    float2* lut = zsm + MDIM*RSC;
    const int tid = threadIdx.x;

    if (tid < MDIM) {
        float s, c; sincosf(2.0f*(float)PI_D*(float)tid/136.0f, &s, &c);  // inverse dir
        lut[tid] = make_float2(c, s);
    }
    const int p  = blockIdx.x;        // 0..1023
    const int u  = p & 1;
    const int v  = (p >> 3) & 1;
    const int nc = ((p >> 4) << 2) | ((p >> 1) & 3);   // n*64 + c
    const int c  = nc & 63;
    const float2* Xp = Xhat + (size_t)nc * PLANE_HALF;
    const float2* Ap = Abuf + (size_t)(c*4 + u*2 + v) * PLANE_HALF;

    // Load S = A_uv * Xhat, natural [g1][g2], g2 = 0..68. (S is Hermitian.)
    {
        int g1 = tid / HC, g2 = tid - (tid/HC)*HC;
        for (int e = tid; e < PLANE_HALF; e += NTH) {
            float2 xv = Xp[e], av = Ap[e];
            z[g1*RSC + g2] = make_float2(av.x*xv.x - av.y*xv.y,
                                         av.x*xv.y + av.y*xv.x);
            g1 += 14; g2 += 58; if (g2 >= HC) { g2 -= HC; g1++; }
        }
    }
    __syncthreads();
    fft136_s1<1>(z, lut, HC, tid);                   // columns stage 1
    __syncthreads();
    if (tid < HC*8) {                                // columns stage 2 (rows->slot136)
        int cc = tid >> 3, k1 = tid & 7;
        int base = 17*k1*RSC + cc;
        dft17_sink<1>(z, base, RSC, [&](int k2, float re, float im) {
            z[base + k2*RSC] = make_float2(re, im);
        });
    }
    __syncthreads();
    // Fused c2r pack + ct68 stage 1 (rows): item (row, g) owns column residues
    // {g, 17-g} mod 17; computes Zf[j] = c2r(T[j], T[68-j], lut[j]) inline for its
    // 8 (or 4) columns, then both radix-4 butterflies. Col 68 is read-only.
    {
        int row = tid / 9, g = tid - (tid/9)*9;
        for (int e = tid; e < MDIM*9; e += NTH) {
            int base = row*RSC;
            if (g == 0) {
                float2 T0  = z[base],    T17 = z[base+17], T34 = z[base+34],
                       T51 = z[base+51], T68 = z[base+68];
                float2 Z0 = c2r_pack(T0,  T68, lut[0]);
                float2 Z1 = c2r_pack(T17, T51, lut[17]);
                float2 Z2 = c2r_pack(T34, T34, lut[34]);
                float2 Z3 = c2r_pack(T51, T17, lut[51]);
                radix4_tw<1>(z, lut, base, 0, Z0, Z1, Z2, Z3);
            } else {
                int gb = 17 - g;
                float2 Ta0 = z[base+g],    Ta1 = z[base+g+17],
                       Ta2 = z[base+g+34], Ta3 = z[base+g+51];
                float2 Tb0 = z[base+gb],    Tb1 = z[base+gb+17],
                       Tb2 = z[base+gb+34], Tb3 = z[base+gb+51];
                // partner of (g+17*n1) is (gb+17*(3-n1)), and vice versa
                float2 Za0 = c2r_pack(Ta0, Tb3, lut[g]);
                float2 Za1 = c2r_pack(Ta1, Tb2, lut[g+17]);
                float2 Za2 = c2r_pack(Ta2, Tb1, lut[g+34]);
                float2 Za3 = c2r_pack(Ta3, Tb0, lut[g+51]);
                float2 Zb0 = c2r_pack(Tb0, Ta3, lut[gb]);
                float2 Zb1 = c2r_pack(Tb1, Ta2, lut[gb+17]);
                float2 Zb2 = c2r_pack(Tb2, Ta1, lut[gb+34]);
                float2 Zb3 = c2r_pack(Tb3, Ta0, lut[gb+51]);
                radix4_tw<1>(z, lut, base, g,  Za0, Za1, Za2, Za3);
                radix4_tw<1>(z, lut, base, gb, Zb0, Zb1, Zb2, Zb3);
            }
            row += 113; g += 7; if (g >= 9) { g -= 9; row++; }
        }
    }
    __syncthreads();
    if (tid < MDIM*4) {                              // ct68 stage 2, in place
        int row = tid >> 2, k1 = tid & 3;
        int base = row*RSC + 17*k1;
        dft17_sink<1>(z, base, 1, [&](int k2, float re, float im) {
            z[base + k2] = make_float2(re, im);
        });
    }
    __syncthreads();
    // Cropped store, strength-reduced: per thread m is FIXED (e mod 64 invariant
    // under e += 1024), y1 += 16/iter -> LDS addr += 2*RSC, global ptr += 32*256.
    float* op = out + (size_t)nc * (256*256);
    {
        int m  = 2 + (tid & 63);          // [2,66)
        int y1 = 4 + (tid >> 6);          // [4,20); +16 per iter -> [4,132)
        int a  = slot136(y1)*RSC + slot68(m);
        float* rowp = op + (size_t)(2*y1 + u - 8)*256 + 4*m + v - 8;
#pragma unroll
        for (int it = 0; it < 8; ++it) {
            float2 wv = z[a];
            rowp[0] = wv.x;               // y2' = 2m
            rowp[2] = wv.y;               // y2' = 2m+1
            a += 2*RSC;                   // slot136(y1+16) = slot136(y1) + 2
            rowp += 32*256;
        }
    }
}

extern "C" void kernel_launch(void* const* d_in, const int* in_sizes, int n_in,
                              void* d_out, int out_size, void* d_ws, size_t ws_size,
                              hipStream_t stream)
{
    const float* x      = (const float*)d_in[0];
    const float* weight = (const float*)d_in[1];
    const float* bias   = (const float*)d_in[2];
    float* out = (float*)d_out;

    float2* Xhat = (float2*)d_ws;                       // 256 * 9384 * 8B = 19.2 MB
    float2* Abuf = Xhat + (size_t)NPLANES * PLANE_HALF; // 256 * 9384 * 8B = 19.2 MB

    const size_t lds_bytes = (size_t)LDS_CPLX * sizeof(float2);  // 77,248 B
    (void)hipFuncSetAttribute((const void*)fwd_kernel,
                              hipFuncAttributeMaxDynamicSharedMemorySize, (int)lds_bytes);
    (void)hipFuncSetAttribute((const void*)inv_kernel,
                              hipFuncAttributeMaxDynamicSharedMemorySize, (int)lds_bytes);

    prep_kernel<<<512, 256, 0, stream>>>(weight, bias, Abuf);
    fwd_kernel<<<NPLANES, 1024, lds_bytes, stream>>>(x, Xhat);
    inv_kernel<<<NPLANES*4, 1024, lds_bytes, stream>>>(Xhat, Abuf, out);
}

// Round 4
// 144.944 us; speedup vs baseline: 1.1511x; 1.0367x over previous
//
#include <hip/hip_runtime.h>
#include <math.h>

// Converse2D on gfx950 — spectral restructuring (R7):
//   out(2y+u, 2x+v) plane = ifft136( A_uv[g] * Xhat[g] ), per (n,c,u,v)
//   Xhat = rfft136x136(wrap_pad(x)); A_uv = per-channel multiplier (Hermitian).
// R7 (vs R6): inv pairs the two v-parity planes per WG (grid 1024->512,
//   LDS 153,408 B, 1 WG/CU):
//   - final store is dense float4: cols [4m-8..4m-5] = (re_v0, re_v1, im_v0,
//     im_v1) -> one dwordx4 replaces four stride-16B scalar stores
//   - Xhat read once per pair (-25% global load instructions)
//   - stage-2 phases now 1104/1088 items vs 1024 threads (was 552/544 ->
//     half the WG idle at barriers)
//   fwd/prep unchanged from R6.

#define MDIM 136
#define RSC  70             // padded LDS row stride in complex elements (69 + 1)
#define HC   69             // stored Hermitian half columns (0..68)
#define PLANE_HALF (MDIM*HC)   // 9384 complex per plane
#define NPLANES 256         // N*C
#define LDS_CPLX  (MDIM*RSC + MDIM)      // fwd: one plane + LUT (float2 each)
#define LDS_CPLX2 (2*MDIM*RSC + MDIM)    // inv: two planes + LUT
#define PI_D 3.14159265358979323846
#define NTH 1024

__device__ __forceinline__ int slot136(int k) { return 17*(k & 7) + (k >> 3); }
__device__ __forceinline__ int slot68(int k)  { return 17*(k & 3) + (k >> 2); }

// ---------- symmetric 17-point DFT from strided LDS, outputs via sink ----------
template<int DIR, class F>
__device__ __forceinline__ void dft17_sink(float2* z, int base, int stride, F f)
{
    constexpr float C17[9] = {1.f, 0.93247223f, 0.73900892f, 0.44573836f,
                              0.09226836f, -0.27366299f, -0.60263464f,
                              -0.85021714f, -0.98297310f};
    constexpr float S17[9] = {0.f, 0.36124167f, 0.67369564f, 0.89516329f,
                              0.99573418f, 0.96182564f, 0.79801723f,
                              0.52643216f, 0.18374952f};
    constexpr float d = (DIR > 0) ? 1.f : -1.f;
    float xr[17], xi[17];
#pragma unroll
    for (int n = 0; n < 17; n++) {
        float2 v = z[base + n*stride];
        xr[n] = v.x; xi[n] = v.y;
    }
    float ar[8], ai[8], br[8], bi[8];
#pragma unroll
    for (int n = 1; n <= 8; n++) {
        ar[n-1] = xr[n] + xr[17-n];  ai[n-1] = xi[n] + xi[17-n];
        br[n-1] = xr[n] - xr[17-n];  bi[n-1] = xi[n] - xi[17-n];
    }
    float s0r = xr[0], s0i = xi[0];
#pragma unroll
    for (int n = 0; n < 8; n++) { s0r += ar[n]; s0i += ai[n]; }
    f(0, s0r, s0i);
#pragma unroll
    for (int k = 1; k <= 8; k++) {
        float Pr = xr[0], Pi = xi[0], Qr = 0.f, Qi = 0.f;
#pragma unroll
        for (int n = 1; n <= 8; n++) {
            int m = (k*n) % 17;                      // compile-time constant
            float cc = (m <= 8) ? C17[m] : C17[17-m];
            float ss = (m <= 8) ? S17[m] : -S17[17-m];
            Pr = fmaf(ar[n-1], cc, Pr);
            Pi = fmaf(ai[n-1], cc, Pi);
            Qr = fmaf(br[n-1], ss, Qr);
            Qi = fmaf(bi[n-1], ss, Qi);
        }
        f(k,    Pr - d*Qi, Pi + d*Qr);
        f(17-k, Pr + d*Qi, Pi - d*Qr);
    }
}

// ---------- radix-4 butterfly + LUT twiddle, write to col-slots 17*k1 + n2 ----------
template<int DIR>
__device__ __forceinline__ void radix4_tw(float2* z, const float2* lut, int base, int n2,
                                          float2 Z0, float2 Z1, float2 Z2, float2 Z3)
{
    constexpr float d = (DIR > 0) ? 1.0f : -1.0f;
    float t0r = Z0.x+Z2.x, t0i = Z0.y+Z2.y;
    float t1r = Z0.x-Z2.x, t1i = Z0.y-Z2.y;
    float t2r = Z1.x+Z3.x, t2i = Z1.y+Z3.y;
    float t3r = Z1.x-Z3.x, t3i = Z1.y-Z3.y;
    float X0r = t0r+t2r,     X0i = t0i+t2i;
    float X2r = t0r-t2r,     X2i = t0i-t2i;
    float X1r = t1r - d*t3i, X1i = t1i + d*t3r;
    float X3r = t1r + d*t3i, X3i = t1i - d*t3r;
    z[base + n2] = make_float2(X0r, X0i);
    float2 w1 = lut[2*n2], w2 = lut[4*n2], w3 = lut[6*n2];   // w68^(k1*n2), idx<=96
    z[base + 17 + n2] = make_float2(X1r*w1.x - X1i*w1.y, X1r*w1.y + X1i*w1.x);
    z[base + 34 + n2] = make_float2(X2r*w2.x - X2i*w2.y, X2r*w2.y + X2i*w2.x);
    z[base + 51 + n2] = make_float2(X3r*w3.x - X3i*w3.y, X3r*w3.y + X3i*w3.x);
}

// ---------- 136-point CT stage 1 (radix-8 + LUT twiddle), single plane ----------
template<int DIR>
__device__ __forceinline__ void fft136_s1_body(float2* z, const float2* lut,
                                               int c, int n2)
{
    constexpr float d = (DIR > 0) ? 1.0f : -1.0f;
    constexpr float C707 = 0.70710678118654752f;
    float xr[8], xi[8];
#pragma unroll
    for (int n1 = 0; n1 < 8; n1++) {
        float2 v = z[(17*n1 + n2)*RSC + c];
        xr[n1] = v.x; xi[n1] = v.y;
    }
    float e0r = xr[0]+xr[4], e0i = xi[0]+xi[4];
    float e1r = xr[0]-xr[4], e1i = xi[0]-xi[4];
    float o0r = xr[2]+xr[6], o0i = xi[2]+xi[6];
    float o1r = xr[2]-xr[6], o1i = xi[2]-xi[6];
    float E0r = e0r+o0r, E0i = e0i+o0i;
    float E2r = e0r-o0r, E2i = e0i-o0i;
    float E1r = e1r - d*o1i, E1i = e1i + d*o1r;
    float E3r = e1r + d*o1i, E3i = e1i - d*o1r;
    float f0r = xr[1]+xr[5], f0i = xi[1]+xi[5];
    float f1r = xr[1]-xr[5], f1i = xi[1]-xi[5];
    float h0r = xr[3]+xr[7], h0i = xi[3]+xi[7];
    float h1r = xr[3]-xr[7], h1i = xi[3]-xi[7];
    float O0r = f0r+h0r, O0i = f0i+h0i;
    float O2r = f0r-h0r, O2i = f0i-h0i;
    float O1r = f1r - d*h1i, O1i = f1i + d*h1r;
    float O3r = f1r + d*h1i, O3i = f1i - d*h1r;
    float t1r =  C707*(O1r - d*O1i), t1i = C707*(O1i + d*O1r);
    float t2r = -d*O2i,              t2i = d*O2r;
    float t3r = -C707*(O3r + d*O3i), t3i = C707*(d*O3r - O3i);
    float Xr[8], Xi[8];
    Xr[0]=E0r+O0r; Xi[0]=E0i+O0i;  Xr[4]=E0r-O0r; Xi[4]=E0i-O0i;
    Xr[1]=E1r+t1r; Xi[1]=E1i+t1i;  Xr[5]=E1r-t1r; Xi[5]=E1i-t1i;
    Xr[2]=E2r+t2r; Xi[2]=E2i+t2i;  Xr[6]=E2r-t2r; Xi[6]=E2i-t2i;
    Xr[3]=E3r+t3r; Xi[3]=E3i+t3i;  Xr[7]=E3r-t3r; Xi[7]=E3i-t3i;
    z[n2*RSC + c] = make_float2(Xr[0], Xi[0]);
    int ti = 0;
#pragma unroll
    for (int k1 = 1; k1 < 8; k1++) {
        ti += n2;                                 // ti = k1*n2 <= 112
        float2 w = lut[ti];
        z[(17*k1 + n2)*RSC + c] = make_float2(Xr[k1]*w.x - Xi[k1]*w.y,
                                              Xr[k1]*w.y + Xi[k1]*w.x);
    }
}

template<int DIR>
__device__ void fft136_s1(float2* z, const float2* lut, int ncols, int tid)
{
    int c = tid / 17;
    int n2 = tid - c*17;
    for (int e = tid; e < ncols*17; e += NTH) {
        fft136_s1_body<DIR>(z, lut, c, n2);
        c += 60; n2 += 4; if (n2 >= 17) { n2 -= 17; c++; }
    }
}

// ---------- 68-point CT stage 1 along ROWS (fwd path: natural input cols) ----------
template<int DIR>
__device__ void ct68_s1(float2* z, const float2* lut, int tid)
{
    int row = tid / 17;
    int n2  = tid - row*17;
    for (int e = tid; e < MDIM*17; e += NTH) {
        int base = row*RSC;
        float2 Z0 = z[base + n2];
        float2 Z1 = z[base + 17 + n2];
        float2 Z2 = z[base + 34 + n2];
        float2 Z3 = z[base + 51 + n2];
        radix4_tw<DIR>(z, lut, base, n2, Z0, Z1, Z2, Z3);
        row += 60; n2 += 4; if (n2 >= 17) { n2 -= 17; row++; }
    }
}

// c2r pack element: Zf[j] from a=T[j], b=T[68-j], w=lut[j] (DIR=+1 LUT).
__device__ __forceinline__ float2 c2r_pack(float2 a, float2 b, float2 w)
{
    float Sr = a.x + b.x, Si = a.y - b.y;
    float Dr = a.x - b.x, Di = a.y + b.y;
    float Or = w.x*Dr - w.y*Di, Oi = w.x*Di + w.y*Dr;
    return make_float2(Sr - Oi, Si + Or);
}

// ---------- Forward: one WG per (n,c) plane (256 WGs), r2c half-spectrum ----------
__global__ __launch_bounds__(1024, 8) void fwd_kernel(const float* __restrict__ x,
                                                      float2* __restrict__ Xhat)
{
    extern __shared__ float2 zsm[];
    float2* z   = zsm;
    float2* lut = zsm + MDIM*RSC;
    const int tid = threadIdx.x;

    if (tid < MDIM) {
        float s, c; sincosf(-2.0f*(float)PI_D*(float)tid/136.0f, &s, &c);
        lut[tid] = make_float2(c, s);
    }
    const float* xp = x + (size_t)blockIdx.x * (128*128);
    // Load packed rows: z[i][n] = xp(i, 2n) + i*xp(i, 2n+1), wrap pad by 4.
    {
        int i = tid / 68, n = tid - (tid/68)*68;
        for (int e = tid; e < MDIM*68; e += NTH) {
            int si = (i + 124) & 127;
            int j0 = (2*n + 124) & 127;              // always even, pair never wraps
            z[i*RSC + n] = *reinterpret_cast<const float2*>(xp + si*128 + j0);
            i += 15; n += 4; if (n >= 68) { n -= 68; i++; }
        }
    }
    __syncthreads();
    ct68_s1<-1>(z, lut, tid);                        // rows stage 1
    __syncthreads();
    if (tid < MDIM*4) {                              // rows stage 2: Z[k] at slot68(k)
        int row = tid >> 2, k1 = tid & 3;
        int base = row*RSC + 17*k1;
        dft17_sink<-1>(z, base, 1, [&](int k2, float re, float im) {
            z[base + k2] = make_float2(re, im);
        });
    }
    __syncthreads();
    // r2c unpack: X[k] = E + w136^k * O ; item k handles (k, 68-k), in-place at slots.
    {
        int row = tid / 35, k = tid - (tid/35)*35;
        for (int e = tid; e < MDIM*35; e += NTH) {
            int base = row*RSC;
            int sa = slot68(k);
            float2 Za = z[base+sa];
            float Zar = Za.x, Zai = Za.y;
            float Zbr, Zbi; int sb;
            if (k == 0) { Zbr = Zar; Zbi = Zai; sb = 68; }  // Z[68]==Z[0]; X[68]->col 68
            else {
                int kk = 68-k; sb = slot68(kk);
                float2 Zb = z[base+sb]; Zbr = Zb.x; Zbi = Zb.y;
            }
            float2 w = lut[k];                              // w136^k (DIR=-1 LUT)
            float wc = w.x, ws = w.y;
            float Er = 0.5f*(Zar + Zbr), Ei = 0.5f*(Zai - Zbi);
            float Dr = 0.5f*(Zar - Zbr), Di = 0.5f*(Zai + Zbi);
            float Tr = wc*Dr - ws*Di, Ti = wc*Di + ws*Dr;   // w^k * D
            z[base+sa] = make_float2(Er + Ti, Ei - Tr);     // X[k] = E - i*(w^k D)
            float E2r = Er,  E2i = -Ei;
            float D2r = -Dr, D2i = Di;
            float w2c = -wc, w2s = ws;                      // w136^(68-k) = -conj(w^k)
            float T2r = w2c*D2r - w2s*D2i, T2i = w2c*D2i + w2s*D2r;
            z[base+sb] = make_float2(E2r + T2i, E2i - T2r); // X[68-k]
            row += 29; k += 9; if (k >= 35) { k -= 35; row++; }
        }
    }
    __syncthreads();
    fft136_s1<-1>(z, lut, HC, tid);                  // columns stage 1 (69 cols)
    __syncthreads();
    if (tid < HC*8) {                                // columns stage 2, in place:
        int c = tid >> 3, k1 = tid & 7;              // freq k1+8k2 at row-slot 17k1+k2
        int base = 17*k1*RSC + c;
        dft17_sink<-1>(z, base, RSC, [&](int k2, float re, float im) {
            z[base + k2*RSC] = make_float2(re, im);
        });
    }
    __syncthreads();
    // Coalesced Xhat store: outp[g1*HC+g2] = z[slot136(g1)*RSC + colslot(g2)].
    float2* outp = Xhat + (size_t)blockIdx.x * PLANE_HALF;
    {
        int g1 = tid / HC, g2 = tid - (tid/HC)*HC;
        for (int e = tid; e < PLANE_HALF; e += NTH) {
            int cq = (g2 == 68) ? 68 : slot68(g2);
            outp[e] = z[slot136(g1)*RSC + cq];
            g1 += 14; g2 += 58; if (g2 >= HC) { g2 -= HC; g1++; }
        }
    }
}

// ---------- Per-channel multiplier precompute (double, table-driven trig) ----------
__global__ void prep_kernel(const float* __restrict__ weight,
                            const float* __restrict__ bias,
                            float2* __restrict__ Abuf)
{
    __shared__ double tabc[272], tabs[272];   // exp(-2*pi*i*t/272)
    for (int t = threadIdx.x; t < 272; t += blockDim.x) {
        double s, c; sincos(-2.0*PI_D*(double)t/272.0, &s, &c);
        tabc[t] = c; tabs[t] = s;
    }
    __syncthreads();

    const int c     = blockIdx.x >> 3;
    const int chunk = blockIdx.x & 7;
    const float* wp = weight + c*25;
    double w[25];
#pragma unroll
    for (int i = 0; i < 25; i++) w[i] = (double)wp[i];
    const double r = 1.0/(1.0 + exp(9.0 - (double)bias[c])) + 1e-5;

    const int e_lo = chunk * 1173;           // 8*1173 == PLANE_HALF
    const int e_hi = e_lo + 1173;
    for (int e = e_lo + (int)threadIdx.x; e < e_hi; e += blockDim.x) {
        int g1 = e / HC, g2 = e - g1*HC;
        double c1 = tabc[g1], s1 = tabs[g1];
        double c2 = tabc[g2], s2 = tabs[g2];
        double e1r[5], e1i[5], e2r[5], e2i[5];
        e1r[2]=1.0; e1i[2]=0.0; e1r[3]=c1; e1i[3]=s1;
        e1r[4]=c1*c1-s1*s1; e1i[4]=2.0*c1*s1;
        e1r[1]=c1; e1i[1]=-s1; e1r[0]=e1r[4]; e1i[0]=-e1i[4];
        e2r[2]=1.0; e2i[2]=0.0; e2r[3]=c2; e2i[3]=s2;
        e2r[4]=c2*c2-s2*s2; e2i[4]=2.0*c2*s2;
        e2r[1]=c2; e2i[1]=-s2; e2r[0]=e2r[4]; e2i[0]=-e2i[4];

        double R0r[5],R0i[5],R1r[5],R1i[5];
#pragma unroll
        for (int a = 0; a < 5; a++) {
            double r0r=0,r0i=0,r1r=0,r1i=0;
#pragma unroll
            for (int b = 0; b < 5; b++) {
                double wv = w[a*5+b];
                double pr = wv*e2r[b], pi = wv*e2i[b];
                r0r += pr; r0i += pi;
                if (b & 1) { r1r -= pr; r1i -= pi; } else { r1r += pr; r1i += pi; }
            }
            R0r[a]=r0r; R0i[a]=r0i; R1r[a]=r1r; R1i[a]=r1i;
        }
        double FBr[2][2], FBi[2][2];
#pragma unroll
        for (int a1 = 0; a1 < 2; a1++)
#pragma unroll
            for (int b1 = 0; b1 < 2; b1++) {
                double fr=0, fi=0;
#pragma unroll
                for (int a = 0; a < 5; a++) {
                    double er = e1r[a], ei = e1i[a];
                    if (a1 && (a & 1)) { er = -er; ei = -ei; }
                    double Rr = b1 ? R1r[a] : R0r[a];
                    double Ri = b1 ? R1i[a] : R0i[a];
                    fr += er*Rr - ei*Ri;
                    fi += er*Ri + ei*Rr;
                }
                FBr[a1][b1]=fr; FBi[a1][b1]=fi;
            }
        double ur[2]={1.0+c1, 1.0-c1}, ui[2]={s1, -s1};
        double vr[2]={1.0+c2, 1.0-c2}, vi[2]={s2, -s2};
        double Br_[2][2], Bi_[2][2];
#pragma unroll
        for (int a1 = 0; a1 < 2; a1++)
#pragma unroll
            for (int b1 = 0; b1 < 2; b1++) {
                Br_[a1][b1] = ur[a1]*vr[b1] - ui[a1]*vi[b1];
                Bi_[a1][b1] = ur[a1]*vi[b1] + ui[a1]*vr[b1];
            }
        double invW=0, Qr=0, Qi=0;
#pragma unroll
        for (int a1 = 0; a1 < 2; a1++)
#pragma unroll
            for (int b1 = 0; b1 < 2; b1++) {
                invW += FBr[a1][b1]*FBr[a1][b1] + FBi[a1][b1]*FBi[a1][b1];
                Qr += FBr[a1][b1]*Br_[a1][b1] - FBi[a1][b1]*Bi_[a1][b1];
                Qi += FBr[a1][b1]*Bi_[a1][b1] + FBi[a1][b1]*Br_[a1][b1];
            }
        invW *= 0.25; Qr *= 0.25; Qi *= 0.25;
        double den = 1.0/(invW + r);
        double Sr = (1.0 - Qr)*den, Si = -Qi*den;
        double Mr[2][2], Mi[2][2];
#pragma unroll
        for (int a1 = 0; a1 < 2; a1++)
#pragma unroll
            for (int b1 = 0; b1 < 2; b1++) {
                Mr[a1][b1] = Br_[a1][b1] + FBr[a1][b1]*Sr + FBi[a1][b1]*Si;
                Mi[a1][b1] = Bi_[a1][b1] + FBr[a1][b1]*Si - FBi[a1][b1]*Sr;
            }
        const double scale = 1.0/73984.0;   // 1/272^2 ifft normalization
#pragma unroll
        for (int uu = 0; uu < 2; uu++)
#pragma unroll
            for (int vv = 0; vv < 2; vv++) {
                double sr=0, si=0;
#pragma unroll
                for (int a1 = 0; a1 < 2; a1++)
#pragma unroll
                    for (int b1 = 0; b1 < 2; b1++) {
                        if ((a1*uu + b1*vv) & 1) { sr -= Mr[a1][b1]; si -= Mi[a1][b1]; }
                        else                     { sr += Mr[a1][b1]; si += Mi[a1][b1]; }
                    }
                int t = g1*uu + g2*vv;                 // <= 203 < 272
                double pc = tabc[t], ps = -tabs[t];    // exp(+i*pi*t/136)
                float2 outv;
                outv.x = (float)((pc*sr - ps*si)*scale);
                outv.y = (float)((pc*si + ps*sr)*scale);
                Abuf[((size_t)(c*4 + uu*2 + vv))*PLANE_HALF + e] = outv;
            }
    }
}

// ---------- Inverse: one WG per (n,c,u) with BOTH v planes (512 WGs) ----------
// blockIdx: u = bit 3, nc = (high<<3)|(low 3) -> the u-pair of an nc is 8 apart
// (same XCD under blockIdx%8 round-robin) so they share Xhat in that L2.
__global__ __launch_bounds__(1024, 4) void inv_kernel(const float2* __restrict__ Xhat,
                                                      const float2* __restrict__ Abuf,
                                                      float* __restrict__ out)
{
    extern __shared__ float2 zsm[];
    float2* z0  = zsm;
    float2* z1  = zsm + MDIM*RSC;
    float2* lut = zsm + 2*MDIM*RSC;
    const int tid = threadIdx.x;

    if (tid < MDIM) {
        float s, c; sincosf(2.0f*(float)PI_D*(float)tid/136.0f, &s, &c);  // inverse dir
        lut[tid] = make_float2(c, s);
    }
    const int p  = blockIdx.x;        // 0..511
    const int u  = (p >> 3) & 1;
    const int nc = ((p >> 4) << 3) | (p & 7);          // n*64 + c
    const int c  = nc & 63;
    const float2* Xp  = Xhat + (size_t)nc * PLANE_HALF;
    const float2* Ap0 = Abuf + (size_t)(c*4 + u*2) * PLANE_HALF;   // v = 0
    const float2* Ap1 = Ap0 + PLANE_HALF;                          // v = 1

    // Load S_v = A_uv * Xhat for both v, natural [g1][g2]. Xhat read ONCE.
    {
        int g1 = tid / HC, g2 = tid - (tid/HC)*HC;
        for (int e = tid; e < PLANE_HALF; e += NTH) {
            float2 xv = Xp[e], a0 = Ap0[e], a1 = Ap1[e];
            int a = g1*RSC + g2;
            z0[a] = make_float2(a0.x*xv.x - a0.y*xv.y, a0.x*xv.y + a0.y*xv.x);
            z1[a] = make_float2(a1.x*xv.x - a1.y*xv.y, a1.x*xv.y + a1.y*xv.x);
            g1 += 14; g2 += 58; if (g2 >= HC) { g2 -= HC; g1++; }
        }
    }
    __syncthreads();
    // Columns stage 1, both planes: 2*69*17 = 2346 items.
    for (int it = tid; it < 2*HC*17; it += NTH) {
        int pl = it >= HC*17;
        int ee = it - (pl ? HC*17 : 0);
        int cc = (ee*241) >> 12;                      // ee/17, ee <= 1172
        int n2 = ee - cc*17;
        fft136_s1_body<1>(pl ? z1 : z0, lut, cc, n2);
    }
    __syncthreads();
    // Columns stage 2, both planes: 2*69*8 = 1104 items (rows -> slot136).
    for (int it = tid; it < 2*HC*8; it += NTH) {
        int pl = it >= HC*8;
        int i  = it - (pl ? HC*8 : 0);
        float2* zz = pl ? z1 : z0;
        int cc = i >> 3, k1 = i & 7;
        int base = 17*k1*RSC + cc;
        dft17_sink<1>(zz, base, RSC, [&](int k2, float re, float im) {
            zz[base + k2*RSC] = make_float2(re, im);
        });
    }
    __syncthreads();
    // Fused c2r pack + ct68 stage 1 (rows), both planes: 2*136*9 = 2448 items.
    for (int it = tid; it < 2*MDIM*9; it += NTH) {
        int pl = it >= MDIM*9;
        int i  = it - (pl ? MDIM*9 : 0);
        float2* zz = pl ? z1 : z0;
        int row = (i*7282) >> 16;                     // i/9, i <= 1223
        int g   = i - row*9;
        int base = row*RSC;
        if (g == 0) {
            float2 T0  = zz[base],    T17 = zz[base+17], T34 = zz[base+34],
                   T51 = zz[base+51], T68 = zz[base+68];
            float2 Z0 = c2r_pack(T0,  T68, lut[0]);
            float2 Z1 = c2r_pack(T17, T51, lut[17]);
            float2 Z2 = c2r_pack(T34, T34, lut[34]);
            float2 Z3 = c2r_pack(T51, T17, lut[51]);
            radix4_tw<1>(zz, lut, base, 0, Z0, Z1, Z2, Z3);
        } else {
            int gb = 17 - g;
            float2 Ta0 = zz[base+g],    Ta1 = zz[base+g+17],
                   Ta2 = zz[base+g+34], Ta3 = zz[base+g+51];
            float2 Tb0 = zz[base+gb],    Tb1 = zz[base+gb+17],
                   Tb2 = zz[base+gb+34], Tb3 = zz[base+gb+51];
            // partner of (g+17*n1) is (gb+17*(3-n1)), and vice versa
            float2 Za0 = c2r_pack(Ta0, Tb3, lut[g]);
            float2 Za1 = c2r_pack(Ta1, Tb2, lut[g+17]);
            float2 Za2 = c2r_pack(Ta2, Tb1, lut[g+34]);
            float2 Za3 = c2r_pack(Ta3, Tb0, lut[g+51]);
            float2 Zb0 = c2r_pack(Tb0, Ta3, lut[gb]);
            float2 Zb1 = c2r_pack(Tb1, Ta2, lut[gb+17]);
            float2 Zb2 = c2r_pack(Tb2, Ta1, lut[gb+34]);
            float2 Zb3 = c2r_pack(Tb3, Ta0, lut[gb+51]);
            radix4_tw<1>(zz, lut, base, g,  Za0, Za1, Za2, Za3);
            radix4_tw<1>(zz, lut, base, gb, Zb0, Zb1, Zb2, Zb3);
        }
    }
    __syncthreads();
    // ct68 stage 2 in place, both planes: 2*136*4 = 1088 items.
    for (int it = tid; it < 2*MDIM*4; it += NTH) {
        int pl = it >= MDIM*4;
        int i  = it - (pl ? MDIM*4 : 0);
        float2* zz = pl ? z1 : z0;
        int row = i >> 2, k1 = i & 3;
        int base = row*RSC + 17*k1;
        dft17_sink<1>(zz, base, 1, [&](int k2, float re, float im) {
            zz[base + k2] = make_float2(re, im);
        });
    }
    __syncthreads();
    // Dense float4 store: cols [4m-8 .. 4m-5] = (re_v0, re_v1, im_v0, im_v1).
    // Strength-reduced: m fixed per thread; y1 += 16/iter -> LDS a += 2*RSC,
    // global rowp += 32*256.
    float* op = out + (size_t)nc * (256*256);
    {
        int m  = 2 + (tid & 63);          // [2,66)
        int y1 = 4 + (tid >> 6);          // [4,20); +16 per iter -> [4,132)
        int a  = slot136(y1)*RSC + slot68(m);
        float* rowp = op + (size_t)(2*y1 + u - 8)*256 + 4*m - 8;
#pragma unroll
        for (int it = 0; it < 8; ++it) {
            float2 w0 = z0[a], w1 = z1[a];
            *reinterpret_cast<float4*>(rowp) = make_float4(w0.x, w1.x, w0.y, w1.y);
            a += 2*RSC;                   // slot136(y1+16) = slot136(y1) + 2
            rowp += 32*256;
        }
    }
}

extern "C" void kernel_launch(void* const* d_in, const int* in_sizes, int n_in,
                              void* d_out, int out_size, void* d_ws, size_t ws_size,
                              hipStream_t stream)
{
    const float* x      = (const float*)d_in[0];
    const float* weight = (const float*)d_in[1];
    const float* bias   = (const float*)d_in[2];
    float* out = (float*)d_out;

    float2* Xhat = (float2*)d_ws;                       // 256 * 9384 * 8B = 19.2 MB
    float2* Abuf = Xhat + (size_t)NPLANES * PLANE_HALF; // 256 * 9384 * 8B = 19.2 MB

    const size_t lds_fwd = (size_t)LDS_CPLX  * sizeof(float2);  //  77,248 B
    const size_t lds_inv = (size_t)LDS_CPLX2 * sizeof(float2);  // 153,408 B
    (void)hipFuncSetAttribute((const void*)fwd_kernel,
                              hipFuncAttributeMaxDynamicSharedMemorySize, (int)lds_fwd);
    (void)hipFuncSetAttribute((const void*)inv_kernel,
                              hipFuncAttributeMaxDynamicSharedMemorySize, (int)lds_inv);

    prep_kernel<<<512, 256, 0, stream>>>(weight, bias, Abuf);
    fwd_kernel<<<NPLANES, 1024, lds_fwd, stream>>>(x, Xhat);
    inv_kernel<<<NPLANES*2, 1024, lds_inv, stream>>>(Xhat, Abuf, out);
}

// Round 5
// 140.699 us; speedup vs baseline: 1.1858x; 1.0302x over previous
//
#include <hip/hip_runtime.h>
#include <math.h>

// Converse2D on gfx950 — spectral restructuring (R8):
//   out(2y+u, 2x+v) plane = ifft136( A_uv[g] * Xhat[g] ), per (n,c,u,v)
//   Xhat = rfft136x136(wrap_pad(x)); A_uv = per-channel multiplier (Hermitian).
// R8 (vs R7): FUSED fwd+inv into one kernel, one WG per (n,c) (grid 256):
//   - Xhat never touches HBM: computed in LDS, captured to registers
//     (10 float2/thread), reused for both u-iterations of the paired-v
//     inverse. Saves 19.2MB write + 38.4MB read + one kernel launch.
//   - A-reads L2-local: WGs sharing channel c are 64 apart -> same XCD.
//   - LDS: 2 planes + fwd/inv LUTs = 154,496 B (1 WG/CU).
//   prep v2: R[a][g2] hoisted to per-block LDS (depends only on c,g2,a),
//   FB via even/odd-a split: ~40% fewer f64 flops, w[25] out of VGPRs.

#define MDIM 136
#define RSC  70             // padded LDS row stride in complex elements (69 + 1)
#define HC   69             // stored Hermitian half columns (0..68)
#define PLANE_HALF (MDIM*HC)   // 9384 complex per plane
#define NPLANES 256         // N*C
#define LDS_CPLX2 (2*MDIM*RSC + 2*MDIM)  // two planes + two LUTs (float2 each)
#define PI_D 3.14159265358979323846
#define NTH 1024

__device__ __forceinline__ int slot136(int k) { return 17*(k & 7) + (k >> 3); }
__device__ __forceinline__ int slot68(int k)  { return 17*(k & 3) + (k >> 2); }

// ---------- symmetric 17-point DFT from strided LDS, outputs via sink ----------
template<int DIR, class F>
__device__ __forceinline__ void dft17_sink(float2* z, int base, int stride, F f)
{
    constexpr float C17[9] = {1.f, 0.93247223f, 0.73900892f, 0.44573836f,
                              0.09226836f, -0.27366299f, -0.60263464f,
                              -0.85021714f, -0.98297310f};
    constexpr float S17[9] = {0.f, 0.36124167f, 0.67369564f, 0.89516329f,
                              0.99573418f, 0.96182564f, 0.79801723f,
                              0.52643216f, 0.18374952f};
    constexpr float d = (DIR > 0) ? 1.f : -1.f;
    float xr[17], xi[17];
#pragma unroll
    for (int n = 0; n < 17; n++) {
        float2 v = z[base + n*stride];
        xr[n] = v.x; xi[n] = v.y;
    }
    float ar[8], ai[8], br[8], bi[8];
#pragma unroll
    for (int n = 1; n <= 8; n++) {
        ar[n-1] = xr[n] + xr[17-n];  ai[n-1] = xi[n] + xi[17-n];
        br[n-1] = xr[n] - xr[17-n];  bi[n-1] = xi[n] - xi[17-n];
    }
    float s0r = xr[0], s0i = xi[0];
#pragma unroll
    for (int n = 0; n < 8; n++) { s0r += ar[n]; s0i += ai[n]; }
    f(0, s0r, s0i);
#pragma unroll
    for (int k = 1; k <= 8; k++) {
        float Pr = xr[0], Pi = xi[0], Qr = 0.f, Qi = 0.f;
#pragma unroll
        for (int n = 1; n <= 8; n++) {
            int m = (k*n) % 17;                      // compile-time constant
            float cc = (m <= 8) ? C17[m] : C17[17-m];
            float ss = (m <= 8) ? S17[m] : -S17[17-m];
            Pr = fmaf(ar[n-1], cc, Pr);
            Pi = fmaf(ai[n-1], cc, Pi);
            Qr = fmaf(br[n-1], ss, Qr);
            Qi = fmaf(bi[n-1], ss, Qi);
        }
        f(k,    Pr - d*Qi, Pi + d*Qr);
        f(17-k, Pr + d*Qi, Pi - d*Qr);
    }
}

// ---------- radix-4 butterfly + LUT twiddle, write to col-slots 17*k1 + n2 ----------
template<int DIR>
__device__ __forceinline__ void radix4_tw(float2* z, const float2* lut, int base, int n2,
                                          float2 Z0, float2 Z1, float2 Z2, float2 Z3)
{
    constexpr float d = (DIR > 0) ? 1.0f : -1.0f;
    float t0r = Z0.x+Z2.x, t0i = Z0.y+Z2.y;
    float t1r = Z0.x-Z2.x, t1i = Z0.y-Z2.y;
    float t2r = Z1.x+Z3.x, t2i = Z1.y+Z3.y;
    float t3r = Z1.x-Z3.x, t3i = Z1.y-Z3.y;
    float X0r = t0r+t2r,     X0i = t0i+t2i;
    float X2r = t0r-t2r,     X2i = t0i-t2i;
    float X1r = t1r - d*t3i, X1i = t1i + d*t3r;
    float X3r = t1r + d*t3i, X3i = t1i - d*t3r;
    z[base + n2] = make_float2(X0r, X0i);
    float2 w1 = lut[2*n2], w2 = lut[4*n2], w3 = lut[6*n2];   // w68^(k1*n2), idx<=96
    z[base + 17 + n2] = make_float2(X1r*w1.x - X1i*w1.y, X1r*w1.y + X1i*w1.x);
    z[base + 34 + n2] = make_float2(X2r*w2.x - X2i*w2.y, X2r*w2.y + X2i*w2.x);
    z[base + 51 + n2] = make_float2(X3r*w3.x - X3i*w3.y, X3r*w3.y + X3i*w3.x);
}

// ---------- 136-point CT stage 1 (radix-8 + LUT twiddle), single plane ----------
template<int DIR>
__device__ __forceinline__ void fft136_s1_body(float2* z, const float2* lut,
                                               int c, int n2)
{
    constexpr float d = (DIR > 0) ? 1.0f : -1.0f;
    constexpr float C707 = 0.70710678118654752f;
    float xr[8], xi[8];
#pragma unroll
    for (int n1 = 0; n1 < 8; n1++) {
        float2 v = z[(17*n1 + n2)*RSC + c];
        xr[n1] = v.x; xi[n1] = v.y;
    }
    float e0r = xr[0]+xr[4], e0i = xi[0]+xi[4];
    float e1r = xr[0]-xr[4], e1i = xi[0]-xi[4];
    float o0r = xr[2]+xr[6], o0i = xi[2]+xi[6];
    float o1r = xr[2]-xr[6], o1i = xi[2]-xi[6];
    float E0r = e0r+o0r, E0i = e0i+o0i;
    float E2r = e0r-o0r, E2i = e0i-o0i;
    float E1r = e1r - d*o1i, E1i = e1i + d*o1r;
    float E3r = e1r + d*o1i, E3i = e1i - d*o1r;
    float f0r = xr[1]+xr[5], f0i = xi[1]+xi[5];
    float f1r = xr[1]-xr[5], f1i = xi[1]-xi[5];
    float h0r = xr[3]+xr[7], h0i = xi[3]+xi[7];
    float h1r = xr[3]-xr[7], h1i = xi[3]-xi[7];
    float O0r = f0r+h0r, O0i = f0i+h0i;
    float O2r = f0r-h0r, O2i = f0i-h0i;
    float O1r = f1r - d*h1i, O1i = f1i + d*h1r;
    float O3r = f1r + d*h1i, O3i = f1i - d*h1r;
    float t1r =  C707*(O1r - d*O1i), t1i = C707*(O1i + d*O1r);
    float t2r = -d*O2i,              t2i = d*O2r;
    float t3r = -C707*(O3r + d*O3i), t3i = C707*(d*O3r - O3i);
    float Xr[8], Xi[8];
    Xr[0]=E0r+O0r; Xi[0]=E0i+O0i;  Xr[4]=E0r-O0r; Xi[4]=E0i-O0i;
    Xr[1]=E1r+t1r; Xi[1]=E1i+t1i;  Xr[5]=E1r-t1r; Xi[5]=E1i-t1i;
    Xr[2]=E2r+t2r; Xi[2]=E2i+t2i;  Xr[6]=E2r-t2r; Xi[6]=E2i-t2i;
    Xr[3]=E3r+t3r; Xi[3]=E3i+t3i;  Xr[7]=E3r-t3r; Xi[7]=E3i-t3i;
    z[n2*RSC + c] = make_float2(Xr[0], Xi[0]);
    int ti = 0;
#pragma unroll
    for (int k1 = 1; k1 < 8; k1++) {
        ti += n2;                                 // ti = k1*n2 <= 112
        float2 w = lut[ti];
        z[(17*k1 + n2)*RSC + c] = make_float2(Xr[k1]*w.x - Xi[k1]*w.y,
                                              Xr[k1]*w.y + Xi[k1]*w.x);
    }
}

template<int DIR>
__device__ void fft136_s1(float2* z, const float2* lut, int ncols, int tid)
{
    int c = tid / 17;
    int n2 = tid - c*17;
    for (int e = tid; e < ncols*17; e += NTH) {
        fft136_s1_body<DIR>(z, lut, c, n2);
        c += 60; n2 += 4; if (n2 >= 17) { n2 -= 17; c++; }
    }
}

// ---------- 68-point CT stage 1 along ROWS (fwd path: natural input cols) ----------
template<int DIR>
__device__ void ct68_s1(float2* z, const float2* lut, int tid)
{
    int row = tid / 17;
    int n2  = tid - row*17;
    for (int e = tid; e < MDIM*17; e += NTH) {
        int base = row*RSC;
        float2 Z0 = z[base + n2];
        float2 Z1 = z[base + 17 + n2];
        float2 Z2 = z[base + 34 + n2];
        float2 Z3 = z[base + 51 + n2];
        radix4_tw<DIR>(z, lut, base, n2, Z0, Z1, Z2, Z3);
        row += 60; n2 += 4; if (n2 >= 17) { n2 -= 17; row++; }
    }
}

// c2r pack element: Zf[j] from a=T[j], b=T[68-j], w=lut[j] (DIR=+1 LUT).
__device__ __forceinline__ float2 c2r_pack(float2 a, float2 b, float2 w)
{
    float Sr = a.x + b.x, Si = a.y - b.y;
    float Dr = a.x - b.x, Di = a.y + b.y;
    float Or = w.x*Dr - w.y*Di, Oi = w.x*Di + w.y*Dr;
    return make_float2(Sr - Oi, Si + Or);
}

// ---------- Fused forward + inverse: one WG per (n,c) plane (256 WGs) ----------
__global__ __launch_bounds__(1024, 4) void conv_kernel(const float* __restrict__ x,
                                                       const float2* __restrict__ Abuf,
                                                       float* __restrict__ out)
{
    extern __shared__ float2 zsm[];
    float2* z0   = zsm;
    float2* z1   = zsm + MDIM*RSC;
    float2* lutI = zsm + 2*MDIM*RSC;   // exp(+2*pi*i*t/136)  (inverse dir)
    float2* lutF = lutI + MDIM;        // exp(-2*pi*i*t/136)  (forward dir)
    const int tid = threadIdx.x;
    const int nc  = blockIdx.x;        // n*64 + c
    const int c   = nc & 63;

    if (tid < MDIM) {
        float s, cc; sincosf(2.0f*(float)PI_D*(float)tid/136.0f, &s, &cc);
        lutI[tid] = make_float2(cc, s);
        lutF[tid] = make_float2(cc, -s);
    }
    // ---------------- forward on z0 ----------------
    const float* xp = x + (size_t)nc * (128*128);
    {   // packed-row load: z0[i][n] = xp(i,2n) + i*xp(i,2n+1), wrap pad by 4
        int i = tid / 68, n = tid - (tid/68)*68;
        for (int e = tid; e < MDIM*68; e += NTH) {
            int si = (i + 124) & 127;
            int j0 = (2*n + 124) & 127;              // always even, pair never wraps
            z0[i*RSC + n] = *reinterpret_cast<const float2*>(xp + si*128 + j0);
            i += 15; n += 4; if (n >= 68) { n -= 68; i++; }
        }
    }
    __syncthreads();
    ct68_s1<-1>(z0, lutF, tid);                      // rows stage 1
    __syncthreads();
    if (tid < MDIM*4) {                              // rows stage 2: Z[k] at slot68(k)
        int row = tid >> 2, k1 = tid & 3;
        int base = row*RSC + 17*k1;
        dft17_sink<-1>(z0, base, 1, [&](int k2, float re, float im) {
            z0[base + k2] = make_float2(re, im);
        });
    }
    __syncthreads();
    {   // r2c unpack: item k handles (k, 68-k), in-place at slots
        int row = tid / 35, k = tid - (tid/35)*35;
        for (int e = tid; e < MDIM*35; e += NTH) {
            int base = row*RSC;
            int sa = slot68(k);
            float2 Za = z0[base+sa];
            float Zar = Za.x, Zai = Za.y;
            float Zbr, Zbi; int sb;
            if (k == 0) { Zbr = Zar; Zbi = Zai; sb = 68; }  // Z[68]==Z[0]; X[68]->col 68
            else {
                int kk = 68-k; sb = slot68(kk);
                float2 Zb = z0[base+sb]; Zbr = Zb.x; Zbi = Zb.y;
            }
            float2 w = lutF[k];                             // w136^k (fwd LUT)
            float wc = w.x, ws = w.y;
            float Er = 0.5f*(Zar + Zbr), Ei = 0.5f*(Zai - Zbi);
            float Dr = 0.5f*(Zar - Zbr), Di = 0.5f*(Zai + Zbi);
            float Tr = wc*Dr - ws*Di, Ti = wc*Di + ws*Dr;   // w^k * D
            z0[base+sa] = make_float2(Er + Ti, Ei - Tr);    // X[k] = E - i*(w^k D)
            float E2r = Er,  E2i = -Ei;
            float D2r = -Dr, D2i = Di;
            float w2c = -wc, w2s = ws;                      // w136^(68-k) = -conj(w^k)
            float T2r = w2c*D2r - w2s*D2i, T2i = w2c*D2i + w2s*D2r;
            z0[base+sb] = make_float2(E2r + T2i, E2i - T2r); // X[68-k]
            row += 29; k += 9; if (k >= 35) { k -= 35; row++; }
        }
    }
    __syncthreads();
    fft136_s1<-1>(z0, lutF, HC, tid);                // columns stage 1 (69 cols)
    __syncthreads();
    if (tid < HC*8) {                                // columns stage 2, in place
        int cc = tid >> 3, k1 = tid & 7;
        int base = 17*k1*RSC + cc;
        dft17_sink<-1>(z0, base, RSC, [&](int k2, float re, float im) {
            z0[base + k2*RSC] = make_float2(re, im);
        });
    }
    __syncthreads();
    // ---------------- capture Xhat to registers ----------------
    // e = tid + 1024k, e = g1*HC + g2; Xhat slot: row slot136(g1), col slot68(g2)/68.
    float2 Xreg[10];
    {
        int g1 = tid / HC, g2 = tid - (tid/HC)*HC;
#pragma unroll
        for (int k = 0; k < 10; k++) {
            if (k < 9 || tid < PLANE_HALF - 9*NTH) {     // tail: 168 threads
                int cq = (g2 == 68) ? 68 : slot68(g2);
                Xreg[k] = z0[slot136(g1)*RSC + cq];
            }
            g1 += 14; g2 += 58; if (g2 >= HC) { g2 -= HC; g1++; }
        }
    }
    __syncthreads();
    // ---------------- inverse, u = 0,1; v-pair in (z0, z1) ----------------
    float* op = out + (size_t)nc * (256*256);
#pragma unroll 1
    for (int u = 0; u < 2; u++) {
        const float2* A0 = Abuf + (size_t)(c*4 + u*2) * PLANE_HALF;  // v = 0
        const float2* A1 = A0 + PLANE_HALF;                          // v = 1
        {   // S_v = A_uv * Xhat, natural [g1][g2]
            int g1 = tid / HC, g2 = tid - (tid/HC)*HC;
#pragma unroll
            for (int k = 0; k < 10; k++) {
                if (k < 9 || tid < PLANE_HALF - 9*NTH) {
                    int e = tid + k*NTH;
                    float2 xv = Xreg[k];
                    float2 a0 = A0[e], a1 = A1[e];
                    int a = g1*RSC + g2;
                    z0[a] = make_float2(a0.x*xv.x - a0.y*xv.y, a0.x*xv.y + a0.y*xv.x);
                    z1[a] = make_float2(a1.x*xv.x - a1.y*xv.y, a1.x*xv.y + a1.y*xv.x);
                }
                g1 += 14; g2 += 58; if (g2 >= HC) { g2 -= HC; g1++; }
            }
        }
        __syncthreads();
        // Columns stage 1, both planes: 2*69*17 = 2346 items.
        for (int it = tid; it < 2*HC*17; it += NTH) {
            int pl = it >= HC*17;
            int ee = it - (pl ? HC*17 : 0);
            int cc = (ee*241) >> 12;                  // ee/17, ee <= 1172
            int n2 = ee - cc*17;
            fft136_s1_body<1>(pl ? z1 : z0, lutI, cc, n2);
        }
        __syncthreads();
        // Columns stage 2, both planes: 2*69*8 = 1104 items (rows -> slot136).
        for (int it = tid; it < 2*HC*8; it += NTH) {
            int pl = it >= HC*8;
            int i  = it - (pl ? HC*8 : 0);
            float2* zz = pl ? z1 : z0;
            int cc = i >> 3, k1 = i & 7;
            int base = 17*k1*RSC + cc;
            dft17_sink<1>(zz, base, RSC, [&](int k2, float re, float im) {
                zz[base + k2*RSC] = make_float2(re, im);
            });
        }
        __syncthreads();
        // Fused c2r pack + ct68 stage 1 (rows), both planes: 2*136*9 = 2448 items.
        for (int it = tid; it < 2*MDIM*9; it += NTH) {
            int pl = it >= MDIM*9;
            int i  = it - (pl ? MDIM*9 : 0);
            float2* zz = pl ? z1 : z0;
            int row = (i*7282) >> 16;                 // i/9, i <= 1223
            int g   = i - row*9;
            int base = row*RSC;
            if (g == 0) {
                float2 T0  = zz[base],    T17 = zz[base+17], T34 = zz[base+34],
                       T51 = zz[base+51], T68 = zz[base+68];
                float2 Z0 = c2r_pack(T0,  T68, lutI[0]);
                float2 Z1 = c2r_pack(T17, T51, lutI[17]);
                float2 Z2 = c2r_pack(T34, T34, lutI[34]);
                float2 Z3 = c2r_pack(T51, T17, lutI[51]);
                radix4_tw<1>(zz, lutI, base, 0, Z0, Z1, Z2, Z3);
            } else {
                int gb = 17 - g;
                float2 Ta0 = zz[base+g],    Ta1 = zz[base+g+17],
                       Ta2 = zz[base+g+34], Ta3 = zz[base+g+51];
                float2 Tb0 = zz[base+gb],    Tb1 = zz[base+gb+17],
                       Tb2 = zz[base+gb+34], Tb3 = zz[base+gb+51];
                // partner of (g+17*n1) is (gb+17*(3-n1)), and vice versa
                float2 Za0 = c2r_pack(Ta0, Tb3, lutI[g]);
                float2 Za1 = c2r_pack(Ta1, Tb2, lutI[g+17]);
                float2 Za2 = c2r_pack(Ta2, Tb1, lutI[g+34]);
                float2 Za3 = c2r_pack(Ta3, Tb0, lutI[g+51]);
                float2 Zb0 = c2r_pack(Tb0, Ta3, lutI[gb]);
                float2 Zb1 = c2r_pack(Tb1, Ta2, lutI[gb+17]);
                float2 Zb2 = c2r_pack(Tb2, Ta1, lutI[gb+34]);
                float2 Zb3 = c2r_pack(Tb3, Ta0, lutI[gb+51]);
                radix4_tw<1>(zz, lutI, base, g,  Za0, Za1, Za2, Za3);
                radix4_tw<1>(zz, lutI, base, gb, Zb0, Zb1, Zb2, Zb3);
            }
        }
        __syncthreads();
        // ct68 stage 2 in place, both planes: 2*136*4 = 1088 items.
        for (int it = tid; it < 2*MDIM*4; it += NTH) {
            int pl = it >= MDIM*4;
            int i  = it - (pl ? MDIM*4 : 0);
            float2* zz = pl ? z1 : z0;
            int row = i >> 2, k1 = i & 3;
            int base = row*RSC + 17*k1;
            dft17_sink<1>(zz, base, 1, [&](int k2, float re, float im) {
                zz[base + k2] = make_float2(re, im);
            });
        }
        __syncthreads();
        // Dense float4 store: cols [4m-8..4m-5] = (re_v0, re_v1, im_v0, im_v1).
        {
            int m  = 2 + (tid & 63);          // [2,66)
            int y1 = 4 + (tid >> 6);          // [4,20); +16/iter -> [4,132)
            int a  = slot136(y1)*RSC + slot68(m);
            float* rowp = op + (size_t)(2*y1 + u - 8)*256 + 4*m - 8;
#pragma unroll
            for (int it = 0; it < 8; ++it) {
                float2 w0 = z0[a], w1 = z1[a];
                *reinterpret_cast<float4*>(rowp) = make_float4(w0.x, w1.x, w0.y, w1.y);
                a += 2*RSC;                   // slot136(y1+16) = slot136(y1) + 2
                rowp += 32*256;
            }
        }
        __syncthreads();                      // z0/z1 reads done before next u writes
    }
}

// ---------- Per-channel multiplier precompute (double, R table in LDS) ----------
__global__ void prep_kernel(const float* __restrict__ weight,
                            const float* __restrict__ bias,
                            float2* __restrict__ Abuf)
{
    __shared__ double tabc[272], tabs[272];   // exp(-2*pi*i*t/272)
    __shared__ double Rs[69*5*4];             // (g2*5+a)*4 + {R0r,R0i,R1r,R1i}
    for (int t = threadIdx.x; t < 272; t += blockDim.x) {
        double s, c; sincos(-2.0*PI_D*(double)t/272.0, &s, &c);
        tabc[t] = c; tabs[t] = s;
    }
    const int c     = blockIdx.x >> 3;
    const int chunk = blockIdx.x & 7;
    const float* wp = weight + c*25;
    const double r = 1.0/(1.0 + exp(9.0 - (double)bias[c])) + 1e-5;
    __syncthreads();
    // R precompute: R{0,1}[a][g2] = sum_b w[a][b] (+/-)^b e2[b](g2). 345 items.
    for (int it = threadIdx.x; it < 69*5; it += blockDim.x) {
        int g2 = it / 5, a = it - 5*g2;
        double c2 = tabc[g2], s2 = tabs[g2];
        double e2r[5], e2i[5];
        e2r[2]=1.0; e2i[2]=0.0; e2r[3]=c2; e2i[3]=s2;
        e2r[4]=c2*c2-s2*s2; e2i[4]=2.0*c2*s2;
        e2r[1]=c2; e2i[1]=-s2; e2r[0]=e2r[4]; e2i[0]=-e2i[4];
        double w0=wp[a*5+0], w1=wp[a*5+1], w2=wp[a*5+2], w3=wp[a*5+3], w4=wp[a*5+4];
        double Rer = w0*e2r[0] + w2*e2r[2] + w4*e2r[4];
        double Rei = w0*e2i[0] + w2*e2i[2] + w4*e2i[4];
        double Ror = w1*e2r[1] + w3*e2r[3];
        double Roi = w1*e2i[1] + w3*e2i[3];
        Rs[it*4+0] = Rer + Ror;  Rs[it*4+1] = Rei + Roi;   // R0
        Rs[it*4+2] = Rer - Ror;  Rs[it*4+3] = Rei - Roi;   // R1
    }
    __syncthreads();

    const int e_lo = chunk * 1173;           // 8*1173 == PLANE_HALF
    const int e_hi = e_lo + 1173;
    int e  = e_lo + (int)threadIdx.x;
    int g1 = e / HC, g2 = e - (e/HC)*HC;
    for (; e < e_hi; e += blockDim.x) {
        double c1 = tabc[g1], s1 = tabs[g1];
        double e1r[5], e1i[5];
        e1r[2]=1.0; e1i[2]=0.0; e1r[3]=c1; e1i[3]=s1;
        e1r[4]=c1*c1-s1*s1; e1i[4]=2.0*c1*s1;
        e1r[1]=c1; e1i[1]=-s1; e1r[0]=e1r[4]; e1i[0]=-e1i[4];

        // FB[a1][b1] = sum_a (+/-)^(a*a1) e1[a] * R[b1][a], via even/odd-a split.
        double FBr[2][2], FBi[2][2];
#pragma unroll
        for (int b1 = 0; b1 < 2; b1++) {
            double Per=0, Pei=0, Por=0, Poi=0;
#pragma unroll
            for (int a = 0; a < 5; a++) {
                double Rr = Rs[(g2*5+a)*4 + 2*b1];
                double Ri = Rs[(g2*5+a)*4 + 2*b1 + 1];
                double tr = e1r[a]*Rr - e1i[a]*Ri;
                double ti = e1r[a]*Ri + e1i[a]*Rr;
                if (a & 1) { Por += tr; Poi += ti; } else { Per += tr; Pei += ti; }
            }
            FBr[0][b1] = Per + Por;  FBi[0][b1] = Pei + Poi;
            FBr[1][b1] = Per - Por;  FBi[1][b1] = Pei - Poi;
        }
        double c2 = tabc[g2], s2 = tabs[g2];
        double ur[2]={1.0+c1, 1.0-c1}, ui[2]={s1, -s1};
        double vr[2]={1.0+c2, 1.0-c2}, vi[2]={s2, -s2};
        double Br_[2][2], Bi_[2][2];
#pragma unroll
        for (int a1 = 0; a1 < 2; a1++)
#pragma unroll
            for (int b1 = 0; b1 < 2; b1++) {
                Br_[a1][b1] = ur[a1]*vr[b1] - ui[a1]*vi[b1];
                Bi_[a1][b1] = ur[a1]*vi[b1] + ui[a1]*vr[b1];
            }
        double invW=0, Qr=0, Qi=0;
#pragma unroll
        for (int a1 = 0; a1 < 2; a1++)
#pragma unroll
            for (int b1 = 0; b1 < 2; b1++) {
                invW += FBr[a1][b1]*FBr[a1][b1] + FBi[a1][b1]*FBi[a1][b1];
                Qr += FBr[a1][b1]*Br_[a1][b1] - FBi[a1][b1]*Bi_[a1][b1];
                Qi += FBr[a1][b1]*Bi_[a1][b1] + FBi[a1][b1]*Br_[a1][b1];
            }
        invW *= 0.25; Qr *= 0.25; Qi *= 0.25;
        double den = 1.0/(invW + r);
        double Sr = (1.0 - Qr)*den, Si = -Qi*den;
        double Mr[2][2], Mi[2][2];
#pragma unroll
        for (int a1 = 0; a1 < 2; a1++)
#pragma unroll
            for (int b1 = 0; b1 < 2; b1++) {
                Mr[a1][b1] = Br_[a1][b1] + FBr[a1][b1]*Sr + FBi[a1][b1]*Si;
                Mi[a1][b1] = Bi_[a1][b1] + FBr[a1][b1]*Si - FBi[a1][b1]*Sr;
            }
        const double scale = 1.0/73984.0;   // 1/272^2 ifft normalization
#pragma unroll
        for (int uu = 0; uu < 2; uu++)
#pragma unroll
            for (int vv = 0; vv < 2; vv++) {
                double sr=0, si=0;
#pragma unroll
                for (int a1 = 0; a1 < 2; a1++)
#pragma unroll
                    for (int b1 = 0; b1 < 2; b1++) {
                        if ((a1*uu + b1*vv) & 1) { sr -= Mr[a1][b1]; si -= Mi[a1][b1]; }
                        else                     { sr += Mr[a1][b1]; si += Mi[a1][b1]; }
                    }
                int t = g1*uu + g2*vv;                 // <= 203 < 272
                double pc = tabc[t], ps = -tabs[t];    // exp(+i*pi*t/136)
                float2 outv;
                outv.x = (float)((pc*sr - ps*si)*scale);
                outv.y = (float)((pc*si + ps*sr)*scale);
                Abuf[((size_t)(c*4 + uu*2 + vv))*PLANE_HALF + e] = outv;
            }
        g1 += 3; g2 += 49; if (g2 >= HC) { g2 -= HC; g1++; }   // e += 256
    }
}

extern "C" void kernel_launch(void* const* d_in, const int* in_sizes, int n_in,
                              void* d_out, int out_size, void* d_ws, size_t ws_size,
                              hipStream_t stream)
{
    const float* x      = (const float*)d_in[0];
    const float* weight = (const float*)d_in[1];
    const float* bias   = (const float*)d_in[2];
    float* out = (float*)d_out;

    float2* Abuf = (float2*)d_ws;     // 256 * 9384 * 8B = 19.2 MB

    const size_t lds_conv = (size_t)LDS_CPLX2 * sizeof(float2);  // 154,496 B
    (void)hipFuncSetAttribute((const void*)conv_kernel,
                              hipFuncAttributeMaxDynamicSharedMemorySize, (int)lds_conv);

    prep_kernel<<<512, 256, 0, stream>>>(weight, bias, Abuf);
    conv_kernel<<<NPLANES, 1024, lds_conv, stream>>>(x, Abuf, out);
}